// Round 1
// baseline (2466.532 us; speedup 1.0000x reference)
//
#include <hip/hip_runtime.h>
#include <hip/hip_bf16.h>

// Problem constants
constexpr int NN   = 50000;   // nodes
constexpr int NE   = 800000;  // edges
constexpr int FIN  = 128;
constexpr int HIDC = 96;
constexpr int FOUT = 64;
constexpr int NHEAD= 8;
constexpr int HCH  = 12;
constexpr int NLAY = 6;
constexpr int EVOC = 1000;
constexpr int EDIM = 32;
constexpr float ACT_SLOPE = 0.01f;
constexpr float ATT_SLOPE = 0.2f;
constexpr float GN_EPS = 1e-5f;
constexpr int GN_BLOCKS = 256;

// ---------------- CSR build ----------------
__global__ void k_hist(const int* __restrict__ dst, int* __restrict__ deg){
    int e = blockIdx.x*blockDim.x + threadIdx.x;
    if(e < NE) atomicAdd(&deg[dst[e]], 1);
}

__global__ __launch_bounds__(1024) void k_scan(const int* __restrict__ deg, int* __restrict__ rowptr){
    __shared__ int sums[1024];
    int tid = threadIdx.x;
    constexpr int CH = (NN + 1023)/1024;
    int base = tid*CH;
    int s = 0;
    for(int i=0;i<CH;i++){ int idx=base+i; if(idx<NN) s += deg[idx]; }
    sums[tid]=s; __syncthreads();
    for(int off=1; off<1024; off<<=1){
        int v = (tid>=off)? sums[tid-off] : 0;
        __syncthreads();
        sums[tid] += v;
        __syncthreads();
    }
    int run = (tid==0)? 0 : sums[tid-1];
    for(int i=0;i<CH;i++){
        int idx=base+i;
        if(idx<NN){ rowptr[idx]=run; run += deg[idx]; }
    }
    if(tid==1023) rowptr[NN]=run;
}

__global__ void k_scatter(const int* __restrict__ src, const int* __restrict__ dst,
                          const int* __restrict__ code, const float* __restrict__ ew,
                          const int* __restrict__ rowptr, int* __restrict__ cursor,
                          int* __restrict__ src_p, int* __restrict__ dst_p,
                          int* __restrict__ code_p, float* __restrict__ ew_p){
    int e = blockIdx.x*blockDim.x + threadIdx.x;
    if(e >= NE) return;
    int d = dst[e];
    int pos = rowptr[d] + atomicAdd(&cursor[d], 1);
    src_p[pos]  = src[e];
    dst_p[pos]  = d;
    code_p[pos] = code[e];
    ew_p[pos]   = ew[e];
}

// ---------------- generic small GEMM: C[M,NC] = A[M,K]@W[K,NC] + bias ----------------
template<int K, int NC>
__global__ __launch_bounds__(256) void k_gemm(const float* __restrict__ A,
        const float* __restrict__ W, const float* __restrict__ bias,
        float* __restrict__ C, int M){
    constexpr bool SW = (K*NC*4 <= 40000);
    constexpr int CPT = NC/16;   // cols per thread (96->6, 64->4)
    __shared__ float At[K][68];  // transposed A tile (64 rows), padded
    __shared__ float Ws[SW ? K*NC : 1];
    int tid = threadIdx.x;
    int m0 = blockIdx.x*64;
    for(int i=tid; i<64*K; i+=256){
        int r = i / K, k = i - r*K;
        int row = m0 + r;
        At[k][r] = (row < M) ? A[row*K + k] : 0.f;
    }
    if constexpr (SW){
        for(int i=tid; i<K*NC; i+=256) Ws[i] = W[i];
    }
    __syncthreads();
    const float* wsrc;
    if constexpr (SW) wsrc = Ws; else wsrc = W;
    int tr = tid>>4, tc = tid&15;
    float acc[4][CPT];
    #pragma unroll
    for(int i=0;i<4;i++)
        #pragma unroll
        for(int j=0;j<CPT;j++) acc[i][j]=0.f;
    #pragma unroll 4
    for(int k=0;k<K;k++){
        float a[4], w[CPT];
        #pragma unroll
        for(int i=0;i<4;i++) a[i] = At[k][tr*4+i];
        #pragma unroll
        for(int j=0;j<CPT;j++) w[j] = wsrc[k*NC + tc*CPT + j];
        #pragma unroll
        for(int i=0;i<4;i++)
            #pragma unroll
            for(int j=0;j<CPT;j++) acc[i][j] += a[i]*w[j];
    }
    #pragma unroll
    for(int i=0;i<4;i++){
        int row = m0 + tr*4 + i;
        if(row < M){
            float* cp = C + row*NC + tc*CPT;
            #pragma unroll
            for(int j=0;j<CPT;j++) cp[j] = acc[i][j] + (bias ? bias[tc*CPT+j] : 0.f);
        }
    }
}

// ---------------- GraphNorm ----------------
__global__ __launch_bounds__(384) void k_gn_reduce(const float* __restrict__ x, float* __restrict__ partial){
    int tid = threadIdx.x;
    float s=0.f, s2=0.f;
    const int total = NN*HIDC;
    const int stride = GN_BLOCKS*384;
    for(int i=blockIdx.x*384+tid; i<total; i+=stride){
        float v = x[i];
        s += v; s2 += v*v;
    }
    __shared__ float ls[384], ls2[384];
    ls[tid]=s; ls2[tid]=s2;
    __syncthreads();
    if(tid < HIDC){
        float a  = ls[tid]+ls[tid+96]+ls[tid+192]+ls[tid+288];
        float b2 = ls2[tid]+ls2[tid+96]+ls2[tid+192]+ls2[tid+288];
        partial[blockIdx.x*192 + tid]      = a;
        partial[blockIdx.x*192 + 96 + tid] = b2;
    }
}

__global__ void k_gn_finalize(const float* __restrict__ partial,
        const float* __restrict__ w, const float* __restrict__ b, const float* __restrict__ ms,
        float* __restrict__ scale, float* __restrict__ shift){
    int c = threadIdx.x;
    if(c >= HIDC) return;
    float s=0.f, s2=0.f;
    for(int bk=0; bk<GN_BLOCKS; bk++){
        s  += partial[bk*192 + c];
        s2 += partial[bk*192 + 96 + c];
    }
    float mean = s / (float)NN;
    float m2   = s2 / (float)NN;
    float msv  = ms[c];
    float var  = m2 - 2.f*msv*mean*mean + msv*msv*mean*mean;
    float sc   = w[c] * rsqrtf(var + GN_EPS);
    scale[c] = sc;
    shift[c] = b[c] - sc*msv*mean;
}

__global__ __launch_bounds__(384) void k_gn_apply(const float* __restrict__ x,
        const float* __restrict__ scale, const float* __restrict__ shift,
        float* __restrict__ out, float slope){
    int tid = threadIdx.x;
    int c = tid % HIDC;
    float sc = scale[c], sh = shift[c];
    const int total = NN*HIDC;
    const int stride = gridDim.x*384;
    for(int i=blockIdx.x*384+tid; i<total; i+=stride){
        float v = sc*x[i] + sh;
        out[i] = (v > 0.f) ? v : slope*v;
    }
}

// ---------------- edge logits ----------------
__global__ __launch_bounds__(256) void k_edge_logits(const float* __restrict__ xl,
        const float* __restrict__ xr, const float* __restrict__ eW,
        const float* __restrict__ att_l,
        const int* __restrict__ src_p, const int* __restrict__ dst_p, const int* __restrict__ code_p,
        float* __restrict__ elog){
    __shared__ float attS[HIDC];
    int tid = threadIdx.x;
    if(tid < HIDC) attS[tid] = att_l[tid];
    __syncthreads();
    int e = blockIdx.x*blockDim.x + tid;
    if(e >= NE) return;
    const float4* a = (const float4*)(xl + src_p[e]*HIDC);
    const float4* b = (const float4*)(xr + dst_p[e]*HIDC);
    const float4* c = (const float4*)(eW + code_p[e]*HIDC);
    float acc[NHEAD];
    #pragma unroll
    for(int h=0;h<NHEAD;h++) acc[h]=0.f;
    #pragma unroll
    for(int j=0;j<24;j++){
        float4 va=a[j], vb=b[j], vc=c[j];
        float sx = va.x+vb.x+vc.x;
        float sy = va.y+vb.y+vc.y;
        float sz = va.z+vb.z+vc.z;
        float sw = va.w+vb.w+vc.w;
        sx = (sx>0.f)? sx : ATT_SLOPE*sx;
        sy = (sy>0.f)? sy : ATT_SLOPE*sy;
        sz = (sz>0.f)? sz : ATT_SLOPE*sz;
        sw = (sw>0.f)? sw : ATT_SLOPE*sw;
        const float* at = &attS[j*4];
        int h = j/3;  // 12 channels per head = 3 float4s
        acc[h] += sx*at[0] + sy*at[1] + sz*at[2] + sw*at[3];
    }
    float* o = elog + e*NHEAD;
    #pragma unroll
    for(int h=0;h<NHEAD;h++) o[h]=acc[h];
}

// ---------------- per-node segment softmax (1 wave per node) ----------------
__global__ __launch_bounds__(256) void k_softmax(const int* __restrict__ rowptr,
        const float* __restrict__ ew_p, float* __restrict__ elog){
    int wave = threadIdx.x >> 6, lane = threadIdx.x & 63;
    int n = blockIdx.x*4 + wave;
    if(n >= NN) return;
    int r0 = rowptr[n], r1 = rowptr[n+1];
    if(r0 >= r1) return;
    int sub = lane >> 3, hd = lane & 7;
    float m = -3.0e38f;
    for(int base=r0; base<r1; base+=8){
        int idx = base + sub;
        float v = (idx < r1) ? elog[idx*NHEAD + hd] : -3.0e38f;
        m = fmaxf(m, v);
    }
    m = fmaxf(m, __shfl_xor(m, 8));
    m = fmaxf(m, __shfl_xor(m, 16));
    m = fmaxf(m, __shfl_xor(m, 32));
    float zs = 0.f;
    for(int base=r0; base<r1; base+=8){
        int idx = base + sub;
        if(idx < r1){
            float p = __expf(elog[idx*NHEAD + hd] - m);
            elog[idx*NHEAD + hd] = p;
            zs += p;
        }
    }
    zs += __shfl_xor(zs, 8);
    zs += __shfl_xor(zs, 16);
    zs += __shfl_xor(zs, 32);
    float inv = 1.f/(zs + 1e-16f);
    for(int base=r0; base<r1; base+=8){
        int idx = base + sub;
        if(idx < r1){
            elog[idx*NHEAD + hd] *= inv * ew_p[idx];
        }
    }
}

// ---------------- aggregate + residual + conv bias ----------------
__global__ __launch_bounds__(128) void k_aggregate(const int* __restrict__ rowptr,
        const int* __restrict__ src_p, const float* __restrict__ elog,
        const float* __restrict__ xl, const float* __restrict__ gbias_l,
        float* __restrict__ h){
    int n = blockIdx.x;
    int c = threadIdx.x;
    if(c >= HIDC) return;
    int r0 = rowptr[n], r1 = rowptr[n+1];
    int hd = c / HCH;
    float acc = 0.f;
    for(int idx=r0; idx<r1; idx++){
        float w = elog[idx*NHEAD + hd];
        int s = src_p[idx];
        acc += w * xl[s*HIDC + c];
    }
    h[n*HIDC + c] += acc + gbias_l[c];
}

// ---------------- launch ----------------
extern "C" void kernel_launch(void* const* d_in, const int* in_sizes, int n_in,
                              void* d_out, int out_size, void* d_ws, size_t ws_size,
                              hipStream_t stream) {
    (void)in_sizes; (void)n_in; (void)out_size; (void)ws_size;
    const float* x          = (const float*)d_in[0];
    const int*   edge_index = (const int*)  d_in[1];
    const float* edge_weight= (const float*)d_in[2];
    const int*   edge_code  = (const int*)  d_in[3];
    const float* edge_emb   = (const float*)d_in[4];
    const float* lin_in_W   = (const float*)d_in[5];
    const float* lin_in_b   = (const float*)d_in[6];
    const float* gn0_w      = (const float*)d_in[7];
    const float* gn0_b      = (const float*)d_in[8];
    const float* gn0_ms     = (const float*)d_in[9];
    const float* Wl         = (const float*)d_in[10];
    const float* bl         = (const float*)d_in[11];
    const float* Wr         = (const float*)d_in[12];
    const float* br         = (const float*)d_in[13];
    const float* We         = (const float*)d_in[14];
    const float* att        = (const float*)d_in[15];
    const float* gbias      = (const float*)d_in[16];
    const float* gn_w       = (const float*)d_in[17];
    const float* gn_b       = (const float*)d_in[18];
    const float* gn_ms      = (const float*)d_in[19];
    const float* lin_out_W  = (const float*)d_in[20];
    const float* lin_out_b  = (const float*)d_in[21];
    float* out = (float*)d_out;

    char* ws = (char*)d_ws;
    size_t off = 0;
    auto alloc = [&](size_t bytes)->void*{ void* p = ws + off; off += (bytes + 255) & ~(size_t)255; return p; };
    float* h     = (float*)alloc((size_t)NN*HIDC*4);
    float* t     = (float*)alloc((size_t)NN*HIDC*4);
    float* xl    = (float*)alloc((size_t)NN*HIDC*4);
    float* xr    = (float*)alloc((size_t)NN*HIDC*4);
    float* elog  = (float*)alloc((size_t)NE*NHEAD*4);
    float* eWa   = (float*)alloc((size_t)NLAY*EVOC*HIDC*4);
    float* partial=(float*)alloc((size_t)GN_BLOCKS*2*HIDC*4);
    float* scale = (float*)alloc(HIDC*4);
    float* shift = (float*)alloc(HIDC*4);
    int* rowptr  = (int*)alloc((size_t)(NN+1)*4);
    int* cursor  = (int*)alloc((size_t)NN*4);
    int* src_p   = (int*)alloc((size_t)NE*4);
    int* dst_p   = (int*)alloc((size_t)NE*4);
    int* code_p  = (int*)alloc((size_t)NE*4);
    float* ew_p  = (float*)alloc((size_t)NE*4);

    const int* src = edge_index;
    const int* dst = edge_index + NE;

    // CSR build (dst constant across layers -> built once per call)
    hipMemsetAsync(cursor, 0, (size_t)NN*4, stream);
    k_hist<<<(NE+255)/256, 256, 0, stream>>>(dst, cursor);
    k_scan<<<1, 1024, 0, stream>>>(cursor, rowptr);
    hipMemsetAsync(cursor, 0, (size_t)NN*4, stream);
    k_scatter<<<(NE+255)/256, 256, 0, stream>>>(src, dst, edge_code, edge_weight,
                                                rowptr, cursor, src_p, dst_p, code_p, ew_p);

    // per-layer edge-vocab transform: eWa[l] = edge_emb @ We[l]  (1000x32x96, tiny)
    for(int l=0;l<NLAY;l++)
        k_gemm<EDIM,HIDC><<<(EVOC+63)/64, 256, 0, stream>>>(edge_emb, We + l*EDIM*HIDC, nullptr,
                                                            eWa + l*EVOC*HIDC, EVOC);

    // lin_in
    k_gemm<FIN,HIDC><<<(NN+63)/64, 256, 0, stream>>>(x, lin_in_W, lin_in_b, h, NN);

    // gn0 (no activation): in-place on h
    k_gn_reduce<<<GN_BLOCKS, 384, 0, stream>>>(h, partial);
    k_gn_finalize<<<1, 128, 0, stream>>>(partial, gn0_w, gn0_b, gn0_ms, scale, shift);
    k_gn_apply<<<768, 384, 0, stream>>>(h, scale, shift, h, 1.0f);

    for(int l=0;l<NLAY;l++){
        k_gn_reduce<<<GN_BLOCKS, 384, 0, stream>>>(h, partial);
        k_gn_finalize<<<1, 128, 0, stream>>>(partial, gn_w + l*HIDC, gn_b + l*HIDC, gn_ms + l*HIDC, scale, shift);
        k_gn_apply<<<768, 384, 0, stream>>>(h, scale, shift, t, ACT_SLOPE);
        k_gemm<HIDC,HIDC><<<(NN+63)/64, 256, 0, stream>>>(t, Wl + l*HIDC*HIDC, bl + l*HIDC, xl, NN);
        k_gemm<HIDC,HIDC><<<(NN+63)/64, 256, 0, stream>>>(t, Wr + l*HIDC*HIDC, br + l*HIDC, xr, NN);
        k_edge_logits<<<(NE+255)/256, 256, 0, stream>>>(xl, xr, eWa + l*EVOC*HIDC, att + l*NHEAD*HCH,
                                                        src_p, dst_p, code_p, elog);
        k_softmax<<<(NN+3)/4, 256, 0, stream>>>(rowptr, ew_p, elog);
        k_aggregate<<<NN, 128, 0, stream>>>(rowptr, src_p, elog, xl, gbias + l*HIDC, h);
    }

    // lin_out -> d_out
    k_gemm<HIDC,FOUT><<<(NN+63)/64, 256, 0, stream>>>(h, lin_out_W, lin_out_b, out, NN);
}

// Round 2
// 2031.736 us; speedup vs baseline: 1.2140x; 1.2140x over previous
//
#include <hip/hip_runtime.h>
#include <hip/hip_bf16.h>

// Problem constants
constexpr int NN   = 50000;   // nodes
constexpr int NE   = 800000;  // edges
constexpr int FIN  = 128;
constexpr int HIDC = 96;
constexpr int FOUT = 64;
constexpr int NHEAD= 8;
constexpr int HCH  = 12;
constexpr int NLAY = 6;
constexpr int EVOC = 1000;
constexpr int EDIM = 32;
constexpr float ACT_SLOPE = 0.01f;
constexpr float ATT_SLOPE = 0.2f;
constexpr float GN_EPS = 1e-5f;
constexpr int GN_BLOCKS = 256;

typedef __hip_bfloat16 bf16;

__device__ __forceinline__ float bfu(unsigned u, int hi){
    return __uint_as_float(hi ? (u & 0xffff0000u) : (u << 16));
}

// ---------------- CSR build ----------------
__global__ void k_hist(const int* __restrict__ dst, int* __restrict__ deg){
    int e = blockIdx.x*blockDim.x + threadIdx.x;
    if(e < NE) atomicAdd(&deg[dst[e]], 1);
}

__global__ __launch_bounds__(1024) void k_scan(const int* __restrict__ deg, int* __restrict__ rowptr){
    __shared__ int sums[1024];
    int tid = threadIdx.x;
    constexpr int CH = (NN + 1023)/1024;
    int base = tid*CH;
    int s = 0;
    for(int i=0;i<CH;i++){ int idx=base+i; if(idx<NN) s += deg[idx]; }
    sums[tid]=s; __syncthreads();
    for(int off=1; off<1024; off<<=1){
        int v = (tid>=off)? sums[tid-off] : 0;
        __syncthreads();
        sums[tid] += v;
        __syncthreads();
    }
    int run = (tid==0)? 0 : sums[tid-1];
    for(int i=0;i<CH;i++){
        int idx=base+i;
        if(idx<NN){ rowptr[idx]=run; run += deg[idx]; }
    }
    if(tid==1023) rowptr[NN]=run;
}

__global__ void k_scatter(const int* __restrict__ src, const int* __restrict__ dst,
                          const int* __restrict__ code, const float* __restrict__ ew,
                          const int* __restrict__ rowptr, int* __restrict__ cursor,
                          int* __restrict__ src_p, int* __restrict__ dst_p,
                          int* __restrict__ code_p, float* __restrict__ ew_p){
    int e = blockIdx.x*blockDim.x + threadIdx.x;
    if(e >= NE) return;
    int d = dst[e];
    int pos = rowptr[d] + atomicAdd(&cursor[d], 1);
    src_p[pos]  = src[e];
    dst_p[pos]  = d;
    code_p[pos] = code[e];
    ew_p[pos]   = ew[e];
}

// -------- small GEMM: C[M,NC] = f(A[M,K])@W[K,NC] + bias, f = GN+LeakyReLU --------
template<int K, int NC, bool GN, typename OT>
__global__ __launch_bounds__(256) void k_gemm(const float* __restrict__ A,
        const float* __restrict__ W, const float* __restrict__ bias,
        const float* __restrict__ gscale, const float* __restrict__ gshift, float slope,
        OT* __restrict__ C, int M){
    constexpr bool SW = (K*NC*4 <= 40000);
    constexpr int CPT = NC/16;   // cols per thread (96->6, 64->4)
    __shared__ float At[K][68];  // transposed A tile (64 rows), padded
    __shared__ float Ws[SW ? K*NC : 1];
    int tid = threadIdx.x;
    int m0 = blockIdx.x*64;
    for(int i=tid; i<64*K; i+=256){
        int r = i / K, k = i - r*K;
        int row = m0 + r;
        float v = (row < M) ? A[row*K + k] : 0.f;
        if constexpr (GN){
            v = gscale[k]*v + gshift[k];
            v = (v > 0.f) ? v : slope*v;
        }
        At[k][r] = v;
    }
    if constexpr (SW){
        for(int i=tid; i<K*NC; i+=256) Ws[i] = W[i];
    }
    __syncthreads();
    const float* wsrc;
    if constexpr (SW) wsrc = Ws; else wsrc = W;
    int tr = tid>>4, tc = tid&15;
    float acc[4][CPT];
    #pragma unroll
    for(int i=0;i<4;i++)
        #pragma unroll
        for(int j=0;j<CPT;j++) acc[i][j]=0.f;
    #pragma unroll 4
    for(int k=0;k<K;k++){
        float a[4], w[CPT];
        #pragma unroll
        for(int i=0;i<4;i++) a[i] = At[k][tr*4+i];
        #pragma unroll
        for(int j=0;j<CPT;j++) w[j] = wsrc[k*NC + tc*CPT + j];
        #pragma unroll
        for(int i=0;i<4;i++)
            #pragma unroll
            for(int j=0;j<CPT;j++) acc[i][j] += a[i]*w[j];
    }
    #pragma unroll
    for(int i=0;i<4;i++){
        int row = m0 + tr*4 + i;
        if(row < M){
            OT* cp = C + (size_t)row*NC + tc*CPT;
            #pragma unroll
            for(int j=0;j<CPT;j++){
                float v = acc[i][j] + (bias ? bias[tc*CPT+j] : 0.f);
                if constexpr (sizeof(OT)==2) cp[j] = __float2bfloat16(v);
                else cp[j] = v;
            }
        }
    }
}

// ---------------- GraphNorm stats ----------------
__global__ __launch_bounds__(384) void k_gn_reduce(const float* __restrict__ x, float* __restrict__ partial){
    int tid = threadIdx.x;
    float s=0.f, s2=0.f;
    const int total = NN*HIDC;
    const int stride = GN_BLOCKS*384;
    for(int i=blockIdx.x*384+tid; i<total; i+=stride){
        float v = x[i];
        s += v; s2 += v*v;
    }
    __shared__ float ls[384], ls2[384];
    ls[tid]=s; ls2[tid]=s2;
    __syncthreads();
    if(tid < HIDC){
        float a  = ls[tid]+ls[tid+96]+ls[tid+192]+ls[tid+288];
        float b2 = ls2[tid]+ls2[tid+96]+ls2[tid+192]+ls2[tid+288];
        partial[blockIdx.x*192 + tid]      = a;
        partial[blockIdx.x*192 + 96 + tid] = b2;
    }
}

__global__ void k_gn_finalize(const float* __restrict__ partial,
        const float* __restrict__ w, const float* __restrict__ b, const float* __restrict__ ms,
        float* __restrict__ scale, float* __restrict__ shift){
    int c = threadIdx.x;
    if(c >= HIDC) return;
    float s=0.f, s2=0.f;
    for(int bk=0; bk<GN_BLOCKS; bk++){
        s  += partial[bk*192 + c];
        s2 += partial[bk*192 + 96 + c];
    }
    float mean = s / (float)NN;
    float m2   = s2 / (float)NN;
    float msv  = ms[c];
    float var  = m2 - 2.f*msv*mean*mean + msv*msv*mean*mean;
    float sc   = w[c] * rsqrtf(var + GN_EPS);
    scale[c] = sc;
    shift[c] = b[c] - sc*msv*mean;
}

__global__ __launch_bounds__(384) void k_gn_apply(const float* __restrict__ x,
        const float* __restrict__ scale, const float* __restrict__ shift,
        float* __restrict__ out, float slope){
    int tid = threadIdx.x;
    int c = tid % HIDC;
    float sc = scale[c], sh = shift[c];
    const int total = NN*HIDC;
    const int stride = gridDim.x*384;
    for(int i=blockIdx.x*384+tid; i<total; i+=stride){
        float v = sc*x[i] + sh;
        out[i] = (v > 0.f) ? v : slope*v;
    }
}

// ---------------- edge logits (bf16 gathers) ----------------
__global__ __launch_bounds__(256) void k_edge_logits(const bf16* __restrict__ xl,
        const bf16* __restrict__ xr, const bf16* __restrict__ eW,
        const float* __restrict__ att_l,
        const int* __restrict__ src_p, const int* __restrict__ dst_p, const int* __restrict__ code_p,
        float* __restrict__ elog){
    __shared__ float attS[HIDC];
    int tid = threadIdx.x;
    if(tid < HIDC) attS[tid] = att_l[tid];
    __syncthreads();
    int e = blockIdx.x*blockDim.x + tid;
    if(e >= NE) return;
    const uint4* a = (const uint4*)(xl + (size_t)src_p[e]*HIDC);
    const uint4* b = (const uint4*)(xr + (size_t)dst_p[e]*HIDC);
    const uint4* c = (const uint4*)(eW + (size_t)code_p[e]*HIDC);
    float acc[NHEAD];
    #pragma unroll
    for(int h=0;h<NHEAD;h++) acc[h]=0.f;
    #pragma unroll
    for(int j=0;j<12;j++){   // 12 x 8 bf16 = 96 channels
        uint4 va=a[j], vb=b[j], vc=c[j];
        const unsigned* pa=&va.x; const unsigned* pb=&vb.x; const unsigned* pc=&vc.x;
        #pragma unroll
        for(int k=0;k<8;k++){
            int ch = 8*j + k;
            float s = bfu(pa[k>>1],k&1) + bfu(pb[k>>1],k&1) + bfu(pc[k>>1],k&1);
            s = (s > 0.f) ? s : ATT_SLOPE*s;
            acc[ch/HCH] += s * attS[ch];
        }
    }
    float* o = elog + (size_t)e*NHEAD;
    float4* o4 = (float4*)o;
    o4[0] = make_float4(acc[0],acc[1],acc[2],acc[3]);
    o4[1] = make_float4(acc[4],acc[5],acc[6],acc[7]);
}

// ------- fused segment softmax + aggregate + residual (one block per node) -------
__global__ __launch_bounds__(128) void k_smax_agg(const int* __restrict__ rowptr,
        const int* __restrict__ src_p, const float* __restrict__ ew_p,
        const float* __restrict__ elog, const bf16* __restrict__ xl,
        const float* __restrict__ gbias_l, float* __restrict__ h){
    int n = blockIdx.x;
    int r0 = rowptr[n], r1 = rowptr[n+1];
    __shared__ float sm[NHEAD], sinv[NHEAD];
    int tid = threadIdx.x;
    if(tid < 64){   // wave0: per-head max & sum over this node's edges
        int sub = tid >> 3, hd = tid & 7;
        float m = -3.0e38f;
        for(int base=r0; base<r1; base+=8){
            int idx = base + sub;
            if(idx < r1) m = fmaxf(m, elog[(size_t)idx*NHEAD + hd]);
        }
        m = fmaxf(m, __shfl_xor(m, 8));
        m = fmaxf(m, __shfl_xor(m, 16));
        m = fmaxf(m, __shfl_xor(m, 32));
        float zs = 0.f;
        for(int base=r0; base<r1; base+=8){
            int idx = base + sub;
            if(idx < r1) zs += __expf(elog[(size_t)idx*NHEAD + hd] - m);
        }
        zs += __shfl_xor(zs, 8);
        zs += __shfl_xor(zs, 16);
        zs += __shfl_xor(zs, 32);
        if(sub == 0){ sm[hd] = m; sinv[hd] = 1.f/(zs + 1e-16f); }
    }
    __syncthreads();
    int c = tid;
    if(c < HIDC){
        int hd = c / HCH;
        float m = sm[hd], inv = sinv[hd];
        float acc = 0.f;
        for(int idx=r0; idx<r1; idx++){
            float w = __expf(elog[(size_t)idx*NHEAD + hd] - m) * inv * ew_p[idx];
            acc += w * __bfloat162float(xl[(size_t)src_p[idx]*HIDC + c]);
        }
        h[(size_t)n*HIDC + c] += acc + gbias_l[c];
    }
}

// ---------------- launch ----------------
extern "C" void kernel_launch(void* const* d_in, const int* in_sizes, int n_in,
                              void* d_out, int out_size, void* d_ws, size_t ws_size,
                              hipStream_t stream) {
    (void)in_sizes; (void)n_in; (void)out_size; (void)ws_size;
    const float* x          = (const float*)d_in[0];
    const int*   edge_index = (const int*)  d_in[1];
    const float* edge_weight= (const float*)d_in[2];
    const int*   edge_code  = (const int*)  d_in[3];
    const float* edge_emb   = (const float*)d_in[4];
    const float* lin_in_W   = (const float*)d_in[5];
    const float* lin_in_b   = (const float*)d_in[6];
    const float* gn0_w      = (const float*)d_in[7];
    const float* gn0_b      = (const float*)d_in[8];
    const float* gn0_ms     = (const float*)d_in[9];
    const float* Wl         = (const float*)d_in[10];
    const float* bl         = (const float*)d_in[11];
    const float* Wr         = (const float*)d_in[12];
    const float* br         = (const float*)d_in[13];
    const float* We         = (const float*)d_in[14];
    const float* att        = (const float*)d_in[15];
    const float* gbias      = (const float*)d_in[16];
    const float* gn_w       = (const float*)d_in[17];
    const float* gn_b       = (const float*)d_in[18];
    const float* gn_ms      = (const float*)d_in[19];
    const float* lin_out_W  = (const float*)d_in[20];
    const float* lin_out_b  = (const float*)d_in[21];
    float* out = (float*)d_out;

    char* ws = (char*)d_ws;
    size_t off = 0;
    auto alloc = [&](size_t bytes)->void*{ void* p = ws + off; off += (bytes + 255) & ~(size_t)255; return p; };
    float* h     = (float*)alloc((size_t)NN*HIDC*4);
    bf16*  xl    = (bf16*) alloc((size_t)NN*HIDC*2);
    bf16*  xr    = (bf16*) alloc((size_t)NN*HIDC*2);
    float* elog  = (float*)alloc((size_t)NE*NHEAD*4);
    bf16*  eWa   = (bf16*) alloc((size_t)NLAY*EVOC*HIDC*2);
    float* partial=(float*)alloc((size_t)GN_BLOCKS*2*HIDC*4);
    float* scale = (float*)alloc(HIDC*4);
    float* shift = (float*)alloc(HIDC*4);
    int* rowptr  = (int*)alloc((size_t)(NN+1)*4);
    int* cursor  = (int*)alloc((size_t)NN*4);
    int* src_p   = (int*)alloc((size_t)NE*4);
    int* dst_p   = (int*)alloc((size_t)NE*4);
    int* code_p  = (int*)alloc((size_t)NE*4);
    float* ew_p  = (float*)alloc((size_t)NE*4);

    const int* src = edge_index;
    const int* dst = edge_index + NE;

    // CSR build (dst constant across layers -> built once per call)
    hipMemsetAsync(cursor, 0, (size_t)NN*4, stream);
    k_hist<<<(NE+255)/256, 256, 0, stream>>>(dst, cursor);
    k_scan<<<1, 1024, 0, stream>>>(cursor, rowptr);
    hipMemsetAsync(cursor, 0, (size_t)NN*4, stream);
    k_scatter<<<(NE+255)/256, 256, 0, stream>>>(src, dst, edge_code, edge_weight,
                                                rowptr, cursor, src_p, dst_p, code_p, ew_p);

    // per-layer edge-vocab transform: eWa[l] = edge_emb @ We[l] (1000x32x96) -> bf16
    for(int l=0;l<NLAY;l++)
        k_gemm<EDIM,HIDC,false,bf16><<<(EVOC+63)/64, 256, 0, stream>>>(
            edge_emb, We + l*EDIM*HIDC, nullptr, nullptr, nullptr, 0.f,
            eWa + (size_t)l*EVOC*HIDC, EVOC);

    // lin_in -> h (fp32)
    k_gemm<FIN,HIDC,false,float><<<(NN+63)/64, 256, 0, stream>>>(
        x, lin_in_W, lin_in_b, nullptr, nullptr, 0.f, h, NN);

    // gn0 (no activation), in-place on h
    k_gn_reduce<<<GN_BLOCKS, 384, 0, stream>>>(h, partial);
    k_gn_finalize<<<1, 128, 0, stream>>>(partial, gn0_w, gn0_b, gn0_ms, scale, shift);
    k_gn_apply<<<768, 384, 0, stream>>>(h, scale, shift, h, 1.0f);

    for(int l=0;l<NLAY;l++){
        k_gn_reduce<<<GN_BLOCKS, 384, 0, stream>>>(h, partial);
        k_gn_finalize<<<1, 128, 0, stream>>>(partial, gn_w + l*HIDC, gn_b + l*HIDC, gn_ms + l*HIDC, scale, shift);
        // GN+LeakyReLU fused into A-tile stage; bf16 outputs
        k_gemm<HIDC,HIDC,true,bf16><<<(NN+63)/64, 256, 0, stream>>>(
            h, Wl + (size_t)l*HIDC*HIDC, bl + l*HIDC, scale, shift, ACT_SLOPE, xl, NN);
        k_gemm<HIDC,HIDC,true,bf16><<<(NN+63)/64, 256, 0, stream>>>(
            h, Wr + (size_t)l*HIDC*HIDC, br + l*HIDC, scale, shift, ACT_SLOPE, xr, NN);
        k_edge_logits<<<(NE+255)/256, 256, 0, stream>>>(xl, xr, eWa + (size_t)l*EVOC*HIDC,
                                                        att + l*NHEAD*HCH, src_p, dst_p, code_p, elog);
        k_smax_agg<<<NN, 128, 0, stream>>>(rowptr, src_p, ew_p, elog, xl, gbias + l*HIDC, h);
    }

    // lin_out -> d_out (fp32)
    k_gemm<HIDC,FOUT,false,float><<<(NN+63)/64, 256, 0, stream>>>(
        h, lin_out_W, lin_out_b, nullptr, nullptr, 0.f, out, NN);
}

// Round 3
// 1539.345 us; speedup vs baseline: 1.6023x; 1.3199x over previous
//
#include <hip/hip_runtime.h>
#include <hip/hip_bf16.h>

// Problem constants
constexpr int NN   = 50000;   // nodes
constexpr int NE   = 800000;  // edges
constexpr int FIN  = 128;
constexpr int HIDC = 96;
constexpr int FOUT = 64;
constexpr int NHEAD= 8;
constexpr int HCH  = 12;
constexpr int NLAY = 6;
constexpr int EVOC = 1000;
constexpr int EDIM = 32;
constexpr float ACT_SLOPE = 0.01f;
constexpr float ATT_SLOPE = 0.2f;
constexpr float GN_EPS = 1e-5f;
constexpr int GN_BLOCKS = 256;

typedef __hip_bfloat16 bf16;

__device__ __forceinline__ float bfu(unsigned u, int hi){
    return __uint_as_float(hi ? (u & 0xffff0000u) : (u << 16));
}

// ---------------- CSR build ----------------
__global__ void k_hist(const int* __restrict__ dst, int* __restrict__ deg){
    int e = blockIdx.x*blockDim.x + threadIdx.x;
    if(e < NE) atomicAdd(&deg[dst[e]], 1);
}

__global__ __launch_bounds__(1024) void k_scan(const int* __restrict__ deg, int* __restrict__ rowptr){
    __shared__ int sums[1024];
    int tid = threadIdx.x;
    constexpr int CH = (NN + 1023)/1024;
    int base = tid*CH;
    int s = 0;
    for(int i=0;i<CH;i++){ int idx=base+i; if(idx<NN) s += deg[idx]; }
    sums[tid]=s; __syncthreads();
    for(int off=1; off<1024; off<<=1){
        int v = (tid>=off)? sums[tid-off] : 0;
        __syncthreads();
        sums[tid] += v;
        __syncthreads();
    }
    int run = (tid==0)? 0 : sums[tid-1];
    for(int i=0;i<CH;i++){
        int idx=base+i;
        if(idx<NN){ rowptr[idx]=run; run += deg[idx]; }
    }
    if(tid==1023) rowptr[NN]=run;
}

__global__ void k_scatter(const int* __restrict__ src, const int* __restrict__ dst,
                          const int* __restrict__ code, const float* __restrict__ ew,
                          const int* __restrict__ rowptr, int* __restrict__ cursor,
                          int* __restrict__ src_p, int* __restrict__ code_p,
                          float* __restrict__ ew_p){
    int e = blockIdx.x*blockDim.x + threadIdx.x;
    if(e >= NE) return;
    int d = dst[e];
    int pos = rowptr[d] + atomicAdd(&cursor[d], 1);
    src_p[pos]  = src[e];
    code_p[pos] = code[e];
    ew_p[pos]   = ew[e];
}

// -------- small GEMM: C[M,NC] = f(A[M,K])@W[K,NC] + bias, f = GN+LeakyReLU --------
template<int K, int NC, bool GN, typename OT>
__global__ __launch_bounds__(256) void k_gemm(const float* __restrict__ A,
        const float* __restrict__ W, const float* __restrict__ bias,
        const float* __restrict__ gscale, const float* __restrict__ gshift, float slope,
        OT* __restrict__ C, int M){
    constexpr bool SW = (K*NC*4 <= 40000);
    constexpr int CPT = NC/16;   // cols per thread (96->6, 64->4)
    __shared__ float At[K][68];  // transposed A tile (64 rows), padded
    __shared__ float Ws[SW ? K*NC : 1];
    int tid = threadIdx.x;
    int m0 = blockIdx.x*64;
    for(int i=tid; i<64*K; i+=256){
        int r = i / K, k = i - r*K;
        int row = m0 + r;
        float v = (row < M) ? A[row*K + k] : 0.f;
        if constexpr (GN){
            v = gscale[k]*v + gshift[k];
            v = (v > 0.f) ? v : slope*v;
        }
        At[k][r] = v;
    }
    if constexpr (SW){
        for(int i=tid; i<K*NC; i+=256) Ws[i] = W[i];
    }
    __syncthreads();
    const float* wsrc;
    if constexpr (SW) wsrc = Ws; else wsrc = W;
    int tr = tid>>4, tc = tid&15;
    float acc[4][CPT];
    #pragma unroll
    for(int i=0;i<4;i++)
        #pragma unroll
        for(int j=0;j<CPT;j++) acc[i][j]=0.f;
    #pragma unroll 4
    for(int k=0;k<K;k++){
        float a[4], w[CPT];
        #pragma unroll
        for(int i=0;i<4;i++) a[i] = At[k][tr*4+i];
        #pragma unroll
        for(int j=0;j<CPT;j++) w[j] = wsrc[k*NC + tc*CPT + j];
        #pragma unroll
        for(int i=0;i<4;i++)
            #pragma unroll
            for(int j=0;j<CPT;j++) acc[i][j] += a[i]*w[j];
    }
    #pragma unroll
    for(int i=0;i<4;i++){
        int row = m0 + tr*4 + i;
        if(row < M){
            OT* cp = C + (size_t)row*NC + tc*CPT;
            #pragma unroll
            for(int j=0;j<CPT;j++){
                float v = acc[i][j] + (bias ? bias[tc*CPT+j] : 0.f);
                if constexpr (sizeof(OT)==2) cp[j] = __float2bfloat16(v);
                else cp[j] = v;
            }
        }
    }
}

// ---------------- GraphNorm stats ----------------
__global__ __launch_bounds__(384) void k_gn_reduce(const float* __restrict__ x, float* __restrict__ partial){
    int tid = threadIdx.x;
    float s=0.f, s2=0.f;
    const int total = NN*HIDC;
    const int stride = GN_BLOCKS*384;
    for(int i=blockIdx.x*384+tid; i<total; i+=stride){
        float v = x[i];
        s += v; s2 += v*v;
    }
    __shared__ float ls[384], ls2[384];
    ls[tid]=s; ls2[tid]=s2;
    __syncthreads();
    if(tid < HIDC){
        float a  = ls[tid]+ls[tid+96]+ls[tid+192]+ls[tid+288];
        float b2 = ls2[tid]+ls2[tid+96]+ls2[tid+192]+ls2[tid+288];
        partial[blockIdx.x*192 + tid]      = a;
        partial[blockIdx.x*192 + 96 + tid] = b2;
    }
}

__global__ void k_gn_finalize(const float* __restrict__ partial,
        const float* __restrict__ w, const float* __restrict__ b, const float* __restrict__ ms,
        float* __restrict__ scale, float* __restrict__ shift){
    int c = threadIdx.x;
    if(c >= HIDC) return;
    float s=0.f, s2=0.f;
    for(int bk=0; bk<GN_BLOCKS; bk++){
        s  += partial[bk*192 + c];
        s2 += partial[bk*192 + 96 + c];
    }
    float mean = s / (float)NN;
    float m2   = s2 / (float)NN;
    float msv  = ms[c];
    float var  = m2 - 2.f*msv*mean*mean + msv*msv*mean*mean;
    float sc   = w[c] * rsqrtf(var + GN_EPS);
    scale[c] = sc;
    shift[c] = b[c] - sc*msv*mean;
}

__global__ __launch_bounds__(384) void k_gn_apply(const float* __restrict__ x,
        const float* __restrict__ scale, const float* __restrict__ shift,
        float* __restrict__ out, float slope){
    int tid = threadIdx.x;
    int c = tid % HIDC;
    float sc = scale[c], sh = shift[c];
    const int total = NN*HIDC;
    const int stride = gridDim.x*384;
    for(int i=blockIdx.x*384+tid; i<total; i+=stride){
        float v = sc*x[i] + sh;
        out[i] = (v > 0.f) ? v : slope*v;
    }
}

// ---- fully fused GATv2 edge path: logits + online softmax + aggregate + residual ----
// one block (128 threads) per node; flash-attention-style over incoming edges
__global__ __launch_bounds__(128) void k_gat(const int* __restrict__ rowptr,
        const int* __restrict__ src_p, const int* __restrict__ code_p,
        const float* __restrict__ ew_p,
        const bf16* __restrict__ xl, const bf16* __restrict__ xr,
        const bf16* __restrict__ eW, const float* __restrict__ att_l,
        const float* __restrict__ gbias_l, float* __restrict__ h){
    constexpr int T = 16;                 // edge tile
    int n = blockIdx.x;
    int r0 = rowptr[n], r1 = rowptr[n+1];
    int tid = threadIdx.x;
    __shared__ bf16  xls[T][HIDC];        // staged xl rows (3 KB)
    __shared__ float pl[T][NHEAD];        // logits -> p*ew
    __shared__ float xrS[HIDC];
    __shared__ float attS[HIDC];
    __shared__ float mS[NHEAD], zS[NHEAD], scaleS[NHEAD];
    if(tid < HIDC){
        xrS[tid]  = __bfloat162float(xr[(size_t)n*HIDC + tid]);
        attS[tid] = att_l[tid];
    }
    if(tid < NHEAD){ mS[tid] = -3.0e38f; zS[tid] = 0.f; }
    __syncthreads();
    float acc = 0.f;                      // per-channel accumulator (tid<96)
    int hd = (tid < HIDC) ? tid / HCH : 0;
    int e_loc = tid >> 3;                 // 0..15
    int hh    = tid & 7;                  // head in logit phase
    for(int base = r0; base < r1; base += T){
        int eidx = base + e_loc;
        bool valid = eidx < r1;
        float lg = -3.0e38f;
        uint2* lrow = (uint2*)(&xls[e_loc][0]);
        if(valid){
            int s  = src_p[eidx];
            int cd = code_p[eidx];
            const uint2* xrow2 = (const uint2*)(xl + (size_t)s*HIDC);
            const uint2* erow2 = (const uint2*)(eW + (size_t)cd*HIDC);
            float dot = 0.f;
            #pragma unroll
            for(int q=0;q<3;q++){
                uint2 xa = xrow2[hh*3+q];
                uint2 ea = erow2[hh*3+q];
                lrow[hh*3+q] = xa;        // stage xl row chunk
                const unsigned ua[2] = {xa.x, xa.y};
                const unsigned ub[2] = {ea.x, ea.y};
                #pragma unroll
                for(int k2=0;k2<4;k2++){
                    int ch = hh*HCH + q*4 + k2;
                    float v = bfu(ua[k2>>1], k2&1) + xrS[ch] + bfu(ub[k2>>1], k2&1);
                    v = (v > 0.f) ? v : ATT_SLOPE*v;
                    dot += v * attS[ch];
                }
            }
            lg = dot;
        } else {
            uint2 zz; zz.x = 0u; zz.y = 0u;
            #pragma unroll
            for(int q=0;q<3;q++) lrow[hh*3+q] = zz;
        }
        pl[e_loc][hh] = lg;
        __syncthreads();
        // online per-head max/sum update (8 threads)
        if(tid < NHEAD){
            float tm = -3.0e38f;
            #pragma unroll 4
            for(int e=0;e<T;e++) tm = fmaxf(tm, pl[e][tid]);
            float mo = mS[tid];
            float mn = fmaxf(mo, tm);
            float sc = (mo == -3.0e38f) ? 0.f : __expf(mo - mn);
            float add = 0.f;
            #pragma unroll 4
            for(int e=0;e<T;e++){
                float p = __expf(pl[e][tid] - mn);  // invalid -> exp(-inf)=0
                add += p;
                pl[e][tid] = p;
            }
            mS[tid] = mn;
            scaleS[tid] = sc;
            zS[tid] = zS[tid]*sc + add;
        }
        __syncthreads();
        // fold edge_weight into p (threads (e,h))
        if(eidx < r1) pl[e_loc][hh] *= ew_p[eidx];
        if(tid < HIDC) acc *= scaleS[hd];
        __syncthreads();
        // accumulate tile (96 channel threads)
        if(tid < HIDC){
            #pragma unroll 4
            for(int e=0;e<T;e++)
                acc += pl[e][hd] * __bfloat162float(xls[e][tid]);
        }
        __syncthreads();   // protect LDS before next tile
    }
    if(tid < HIDC){
        float inv = 1.f/(zS[hd] + 1e-16f);
        h[(size_t)n*HIDC + tid] += acc*inv + gbias_l[tid];
    }
}

// ---------------- launch ----------------
extern "C" void kernel_launch(void* const* d_in, const int* in_sizes, int n_in,
                              void* d_out, int out_size, void* d_ws, size_t ws_size,
                              hipStream_t stream) {
    (void)in_sizes; (void)n_in; (void)out_size; (void)ws_size;
    const float* x          = (const float*)d_in[0];
    const int*   edge_index = (const int*)  d_in[1];
    const float* edge_weight= (const float*)d_in[2];
    const int*   edge_code  = (const int*)  d_in[3];
    const float* edge_emb   = (const float*)d_in[4];
    const float* lin_in_W   = (const float*)d_in[5];
    const float* lin_in_b   = (const float*)d_in[6];
    const float* gn0_w      = (const float*)d_in[7];
    const float* gn0_b      = (const float*)d_in[8];
    const float* gn0_ms     = (const float*)d_in[9];
    const float* Wl         = (const float*)d_in[10];
    const float* bl         = (const float*)d_in[11];
    const float* Wr         = (const float*)d_in[12];
    const float* br         = (const float*)d_in[13];
    const float* We         = (const float*)d_in[14];
    const float* att        = (const float*)d_in[15];
    const float* gbias      = (const float*)d_in[16];
    const float* gn_w       = (const float*)d_in[17];
    const float* gn_b       = (const float*)d_in[18];
    const float* gn_ms      = (const float*)d_in[19];
    const float* lin_out_W  = (const float*)d_in[20];
    const float* lin_out_b  = (const float*)d_in[21];
    float* out = (float*)d_out;

    char* ws = (char*)d_ws;
    size_t off = 0;
    auto alloc = [&](size_t bytes)->void*{ void* p = ws + off; off += (bytes + 255) & ~(size_t)255; return p; };
    float* h     = (float*)alloc((size_t)NN*HIDC*4);
    bf16*  xl    = (bf16*) alloc((size_t)NN*HIDC*2);
    bf16*  xr    = (bf16*) alloc((size_t)NN*HIDC*2);
    bf16*  eWa   = (bf16*) alloc((size_t)NLAY*EVOC*HIDC*2);
    float* partial=(float*)alloc((size_t)GN_BLOCKS*2*HIDC*4);
    float* scale = (float*)alloc(HIDC*4);
    float* shift = (float*)alloc(HIDC*4);
    int* rowptr  = (int*)alloc((size_t)(NN+1)*4);
    int* cursor  = (int*)alloc((size_t)NN*4);
    int* src_p   = (int*)alloc((size_t)NE*4);
    int* code_p  = (int*)alloc((size_t)NE*4);
    float* ew_p  = (float*)alloc((size_t)NE*4);

    const int* src = edge_index;
    const int* dst = edge_index + NE;

    // CSR build (dst constant across layers -> built once per call)
    hipMemsetAsync(cursor, 0, (size_t)NN*4, stream);
    k_hist<<<(NE+255)/256, 256, 0, stream>>>(dst, cursor);
    k_scan<<<1, 1024, 0, stream>>>(cursor, rowptr);
    hipMemsetAsync(cursor, 0, (size_t)NN*4, stream);
    k_scatter<<<(NE+255)/256, 256, 0, stream>>>(src, dst, edge_code, edge_weight,
                                                rowptr, cursor, src_p, code_p, ew_p);

    // per-layer edge-vocab transform: eWa[l] = edge_emb @ We[l] (1000x32x96) -> bf16
    for(int l=0;l<NLAY;l++)
        k_gemm<EDIM,HIDC,false,bf16><<<(EVOC+63)/64, 256, 0, stream>>>(
            edge_emb, We + l*EDIM*HIDC, nullptr, nullptr, nullptr, 0.f,
            eWa + (size_t)l*EVOC*HIDC, EVOC);

    // lin_in -> h (fp32)
    k_gemm<FIN,HIDC,false,float><<<(NN+63)/64, 256, 0, stream>>>(
        x, lin_in_W, lin_in_b, nullptr, nullptr, 0.f, h, NN);

    // gn0 (no activation), in-place on h
    k_gn_reduce<<<GN_BLOCKS, 384, 0, stream>>>(h, partial);
    k_gn_finalize<<<1, 128, 0, stream>>>(partial, gn0_w, gn0_b, gn0_ms, scale, shift);
    k_gn_apply<<<768, 384, 0, stream>>>(h, scale, shift, h, 1.0f);

    for(int l=0;l<NLAY;l++){
        k_gn_reduce<<<GN_BLOCKS, 384, 0, stream>>>(h, partial);
        k_gn_finalize<<<1, 128, 0, stream>>>(partial, gn_w + l*HIDC, gn_b + l*HIDC, gn_ms + l*HIDC, scale, shift);
        // GN+LeakyReLU fused into A-tile stage; bf16 outputs
        k_gemm<HIDC,HIDC,true,bf16><<<(NN+63)/64, 256, 0, stream>>>(
            h, Wl + (size_t)l*HIDC*HIDC, bl + l*HIDC, scale, shift, ACT_SLOPE, xl, NN);
        k_gemm<HIDC,HIDC,true,bf16><<<(NN+63)/64, 256, 0, stream>>>(
            h, Wr + (size_t)l*HIDC*HIDC, br + l*HIDC, scale, shift, ACT_SLOPE, xr, NN);
        // fused logits + online softmax + aggregate + residual
        k_gat<<<NN, 128, 0, stream>>>(rowptr, src_p, code_p, ew_p, xl, xr,
                                      eWa + (size_t)l*EVOC*HIDC, att + l*NHEAD*HCH,
                                      gbias + l*HIDC, h);
    }

    // lin_out -> d_out (fp32)
    k_gemm<HIDC,FOUT,false,float><<<(NN+63)/64, 256, 0, stream>>>(
        h, lin_out_W, lin_out_b, nullptr, nullptr, 0.f, out, NN);
}

// Round 4
// 1237.990 us; speedup vs baseline: 1.9924x; 1.2434x over previous
//
#include <hip/hip_runtime.h>
#include <hip/hip_bf16.h>

// Problem constants
constexpr int NN   = 50000;   // nodes
constexpr int NE   = 800000;  // edges
constexpr int FIN  = 128;
constexpr int HIDC = 96;
constexpr int FOUT = 64;
constexpr int NHEAD= 8;
constexpr int HCH  = 12;
constexpr int NLAY = 6;
constexpr int EVOC = 1000;
constexpr int EDIM = 32;
constexpr float ACT_SLOPE = 0.01f;
constexpr float ATT_SLOPE = 0.2f;
constexpr float GN_EPS = 1e-5f;
constexpr int GN_BLOCKS = 256;

typedef __hip_bfloat16 bf16;

__device__ __forceinline__ float bfu(unsigned u, int hi){
    return __uint_as_float(hi ? (u & 0xffff0000u) : (u << 16));
}

// ---------------- CSR build ----------------
__global__ void k_hist(const int* __restrict__ dst, int* __restrict__ deg){
    int e = blockIdx.x*blockDim.x + threadIdx.x;
    if(e < NE) atomicAdd(&deg[dst[e]], 1);
}

__global__ __launch_bounds__(1024) void k_scan(const int* __restrict__ deg, int* __restrict__ rowptr){
    __shared__ int sums[1024];
    int tid = threadIdx.x;
    constexpr int CH = (NN + 1023)/1024;
    int base = tid*CH;
    int s = 0;
    for(int i=0;i<CH;i++){ int idx=base+i; if(idx<NN) s += deg[idx]; }
    sums[tid]=s; __syncthreads();
    for(int off=1; off<1024; off<<=1){
        int v = (tid>=off)? sums[tid-off] : 0;
        __syncthreads();
        sums[tid] += v;
        __syncthreads();
    }
    int run = (tid==0)? 0 : sums[tid-1];
    for(int i=0;i<CH;i++){
        int idx=base+i;
        if(idx<NN){ rowptr[idx]=run; run += deg[idx]; }
    }
    if(tid==1023) rowptr[NN]=run;
}

__global__ void k_scatter(const int* __restrict__ src, const int* __restrict__ dst,
                          const int* __restrict__ code, const float* __restrict__ ew,
                          const int* __restrict__ rowptr, int* __restrict__ cursor,
                          int* __restrict__ src_p, int* __restrict__ code_p,
                          float* __restrict__ ew_p){
    int e = blockIdx.x*blockDim.x + threadIdx.x;
    if(e >= NE) return;
    int d = dst[e];
    int pos = rowptr[d] + atomicAdd(&cursor[d], 1);
    src_p[pos]  = src[e];
    code_p[pos] = code[e];
    ew_p[pos]   = ew[e];
}

// -------- small GEMM: C[M,NC] = f(A[M,K])@W[K,NC] + bias, f = GN+LeakyReLU --------
// W read through L1/L2 (broadcast across blocks); LDS holds only the A tile
// -> 26 KB LDS -> ~6 blocks/CU instead of 2.
template<int K, int NC, bool GN, typename OT>
__global__ __launch_bounds__(256) void k_gemm(const float* __restrict__ A,
        const float* __restrict__ W, const float* __restrict__ bias,
        const float* __restrict__ gscale, const float* __restrict__ gshift, float slope,
        OT* __restrict__ C, int M, int wstride, int cstride){
    constexpr int CPT = NC/16;   // cols per thread (96->6, 64->4)
    W += (size_t)blockIdx.y * wstride;
    C += (size_t)blockIdx.y * cstride;
    __shared__ float At[K][68];  // transposed A tile (64 rows), padded
    int tid = threadIdx.x;
    int m0 = blockIdx.x*64;
    for(int i=tid; i<64*K; i+=256){
        int r = i / K, k = i - r*K;
        int row = m0 + r;
        float v = (row < M) ? A[(size_t)row*K + k] : 0.f;
        if constexpr (GN){
            v = gscale[k]*v + gshift[k];
            v = (v > 0.f) ? v : slope*v;
        }
        At[k][r] = v;
    }
    __syncthreads();
    int tr = tid>>4, tc = tid&15;
    const float* wr = W + tc*CPT;
    float acc[4][CPT];
    #pragma unroll
    for(int i=0;i<4;i++)
        #pragma unroll
        for(int j=0;j<CPT;j++) acc[i][j]=0.f;
    #pragma unroll 4
    for(int k=0;k<K;k++){
        float a[4], w[CPT];
        #pragma unroll
        for(int i=0;i<4;i++) a[i] = At[k][tr*4+i];
        #pragma unroll
        for(int j=0;j<CPT;j++) w[j] = wr[k*NC + j];
        #pragma unroll
        for(int i=0;i<4;i++)
            #pragma unroll
            for(int j=0;j<CPT;j++) acc[i][j] += a[i]*w[j];
    }
    #pragma unroll
    for(int i=0;i<4;i++){
        int row = m0 + tr*4 + i;
        if(row < M){
            OT* cp = C + (size_t)row*NC + tc*CPT;
            #pragma unroll
            for(int j=0;j<CPT;j++){
                float v = acc[i][j] + (bias ? bias[tc*CPT+j] : 0.f);
                if constexpr (sizeof(OT)==2) cp[j] = __float2bfloat16(v);
                else cp[j] = v;
            }
        }
    }
}

// ---------------- GraphNorm stats ----------------
__global__ __launch_bounds__(384) void k_gn_reduce(const float* __restrict__ x, float* __restrict__ partial){
    int tid = threadIdx.x;
    float s=0.f, s2=0.f;
    const int total = NN*HIDC;
    const int stride = GN_BLOCKS*384;
    for(int i=blockIdx.x*384+tid; i<total; i+=stride){
        float v = x[i];
        s += v; s2 += v*v;
    }
    __shared__ float ls[384], ls2[384];
    ls[tid]=s; ls2[tid]=s2;
    __syncthreads();
    if(tid < HIDC){
        float a  = ls[tid]+ls[tid+96]+ls[tid+192]+ls[tid+288];
        float b2 = ls2[tid]+ls2[tid+96]+ls2[tid+192]+ls2[tid+288];
        partial[blockIdx.x*192 + tid]      = a;
        partial[blockIdx.x*192 + 96 + tid] = b2;
    }
}

__global__ __launch_bounds__(768) void k_gn_finalize(const float* __restrict__ partial,
        const float* __restrict__ w, const float* __restrict__ b, const float* __restrict__ ms,
        float* __restrict__ scale, float* __restrict__ shift){
    __shared__ float red[4][192];
    int tid = threadIdx.x;
    int v = tid % 192, seg = tid / 192;   // 4 segments
    float s = 0.f;
    #pragma unroll 8
    for(int bk=seg; bk<GN_BLOCKS; bk+=4) s += partial[bk*192 + v];
    red[seg][v] = s;
    __syncthreads();
    if(tid < 192) red[0][tid] = red[0][tid]+red[1][tid]+red[2][tid]+red[3][tid];
    __syncthreads();
    if(tid < HIDC){
        float mean = red[0][tid] / (float)NN;
        float m2   = red[0][tid+96] / (float)NN;
        float mm   = ms[tid]*mean;
        float var  = m2 - 2.f*mm*mean + mm*mm;
        float sc   = w[tid] * rsqrtf(var + GN_EPS);
        scale[tid] = sc;
        shift[tid] = b[tid] - sc*mm;
    }
}

__global__ __launch_bounds__(384) void k_gn_apply(const float* __restrict__ x,
        const float* __restrict__ scale, const float* __restrict__ shift,
        float* __restrict__ out, float slope){
    int tid = threadIdx.x;
    int c = tid % HIDC;
    float sc = scale[c], sh = shift[c];
    const int total = NN*HIDC;
    const int stride = gridDim.x*384;
    for(int i=blockIdx.x*384+tid; i<total; i+=stride){
        float v = sc*x[i] + sh;
        out[i] = (v > 0.f) ? v : slope*v;
    }
}

// ---- fully fused GATv2 edge path, wave-per-node, barrier-free ----
// 64 lanes = (8 edges x 8 heads). Online softmax via shfl over e-bits (8/16/32).
// Cross-lane traffic (staged xl rows, p*ew, head scale/z) via per-wave LDS slice;
// LDS ops complete in-order within a wave -> no s_barrier needed.
__global__ __launch_bounds__(256) void k_gat(const int* __restrict__ rowptr,
        const int* __restrict__ src_p, const int* __restrict__ code_p,
        const float* __restrict__ ew_p,
        const bf16* __restrict__ xl, const bf16* __restrict__ xr,
        const bf16* __restrict__ eW, const float* __restrict__ att_l,
        const float* __restrict__ gbias_l, float* __restrict__ h){
    int wid  = threadIdx.x >> 6;
    int lane = threadIdx.x & 63;
    int n = blockIdx.x*4 + wid;
    __shared__ bf16  xls[4][8][104];   // padded: write banks spread per e
    __shared__ float pl[4][8][NHEAD];
    __shared__ float sS[4][NHEAD];
    __shared__ float zS[4][NHEAD];
    if(n >= NN) return;
    int r0 = rowptr[n], r1 = rowptr[n+1];
    int e_loc = lane >> 3, hh = lane & 7;
    // hoisted per-lane invariants: xr chunk + att chunk for head hh
    float xrh[HCH], ath[HCH];
    {
        const uint2* x2 = (const uint2*)(xr + (size_t)n*HIDC + hh*HCH);
        #pragma unroll
        for(int q=0;q<3;q++){
            uint2 u = x2[q];
            xrh[q*4+0]=bfu(u.x,0); xrh[q*4+1]=bfu(u.x,1);
            xrh[q*4+2]=bfu(u.y,0); xrh[q*4+3]=bfu(u.y,1);
        }
        const float4* a4 = (const float4*)(att_l + hh*HCH);
        #pragma unroll
        for(int q=0;q<3;q++){
            float4 f = a4[q];
            ath[q*4+0]=f.x; ath[q*4+1]=f.y; ath[q*4+2]=f.z; ath[q*4+3]=f.w;
        }
    }
    float m = -3.0e38f, z = 0.f;
    float acc0 = 0.f, acc1 = 0.f;
    const int c0 = lane;               // channel for all lanes
    const int c1 = 64 + (lane & 31);   // extra channel for lanes < 32
    const int hd0 = c0 / HCH;
    const int hd1 = c1 / HCH;
    for(int base = r0; base < r1; base += 8){
        int eidx = base + e_loc;
        float lg = -3.0e38f, ew = 0.f;
        uint2 stv[3]; uint2 ebv[3];
        #pragma unroll
        for(int q=0;q<3;q++){ stv[q] = make_uint2(0u,0u); ebv[q] = stv[q]; }
        if(eidx < r1){
            int s  = src_p[eidx];
            int cd = code_p[eidx];
            ew = ew_p[eidx];
            const uint2* xa = (const uint2*)(xl + (size_t)s*HIDC + hh*HCH);
            const uint2* eb = (const uint2*)(eW + (size_t)cd*HIDC + hh*HCH);
            #pragma unroll
            for(int q=0;q<3;q++){ stv[q] = xa[q]; ebv[q] = eb[q]; }
            float dot = 0.f;
            #pragma unroll
            for(int q=0;q<3;q++){
                unsigned ux[2] = {stv[q].x, stv[q].y};
                unsigned ue[2] = {ebv[q].x, ebv[q].y};
                #pragma unroll
                for(int k2=0;k2<4;k2++){
                    float v = bfu(ux[k2>>1], k2&1) + xrh[q*4+k2] + bfu(ue[k2>>1], k2&1);
                    v = (v > 0.f) ? v : ATT_SLOPE*v;
                    dot += v * ath[q*4+k2];
                }
            }
            lg = dot;
        }
        // stage xl chunk (zeros for invalid edges)
        uint2* d2 = (uint2*)(&xls[wid][e_loc][hh*HCH]);
        d2[0]=stv[0]; d2[1]=stv[1]; d2[2]=stv[2];
        // online softmax update, per head (reduce over e-bits = lane bits 3..5)
        float tm = lg;
        tm = fmaxf(tm, __shfl_xor(tm, 8));
        tm = fmaxf(tm, __shfl_xor(tm, 16));
        tm = fmaxf(tm, __shfl_xor(tm, 32));
        float mn = fmaxf(m, tm);
        float sc = __expf(m - mn);      // first tile: exp(-3e38) = 0
        float p  = __expf(lg - mn);     // invalid lanes: 0
        float zt = p;
        zt += __shfl_xor(zt, 8); zt += __shfl_xor(zt, 16); zt += __shfl_xor(zt, 32);
        z = z*sc + zt;
        m = mn;
        pl[wid][e_loc][hh] = p * ew;
        if(lane < NHEAD) sS[wid][lane] = sc;   // lanes 0..7: e_loc=0, hh=lane
        __builtin_amdgcn_wave_barrier();
        asm volatile("" ::: "memory");
        // aggregate this tile (all lanes busy; lanes<32 carry a 2nd channel)
        float s0 = sS[wid][hd0];
        float a0 = 0.f;
        #pragma unroll
        for(int e=0;e<8;e++)
            a0 += pl[wid][e][hd0] * __bfloat162float(xls[wid][e][c0]);
        acc0 = acc0*s0 + a0;
        if(lane < 32){
            float s1 = sS[wid][hd1];
            float a1 = 0.f;
            #pragma unroll
            for(int e=0;e<8;e++)
                a1 += pl[wid][e][hd1] * __bfloat162float(xls[wid][e][c1]);
            acc1 = acc1*s1 + a1;
        }
        asm volatile("" ::: "memory");
        __builtin_amdgcn_wave_barrier();
    }
    if(lane < NHEAD) zS[wid][lane] = z;
    __builtin_amdgcn_wave_barrier();
    asm volatile("" ::: "memory");
    float z0 = zS[wid][hd0];
    h[(size_t)n*HIDC + c0] += acc0/(z0 + 1e-16f) + gbias_l[c0];
    if(lane < 32){
        float z1 = zS[wid][hd1];
        h[(size_t)n*HIDC + c1] += acc1/(z1 + 1e-16f) + gbias_l[c1];
    }
}

// ---------------- launch ----------------
extern "C" void kernel_launch(void* const* d_in, const int* in_sizes, int n_in,
                              void* d_out, int out_size, void* d_ws, size_t ws_size,
                              hipStream_t stream) {
    (void)in_sizes; (void)n_in; (void)out_size; (void)ws_size;
    const float* x          = (const float*)d_in[0];
    const int*   edge_index = (const int*)  d_in[1];
    const float* edge_weight= (const float*)d_in[2];
    const int*   edge_code  = (const int*)  d_in[3];
    const float* edge_emb   = (const float*)d_in[4];
    const float* lin_in_W   = (const float*)d_in[5];
    const float* lin_in_b   = (const float*)d_in[6];
    const float* gn0_w      = (const float*)d_in[7];
    const float* gn0_b      = (const float*)d_in[8];
    const float* gn0_ms     = (const float*)d_in[9];
    const float* Wl         = (const float*)d_in[10];
    const float* bl         = (const float*)d_in[11];
    const float* Wr         = (const float*)d_in[12];
    const float* br         = (const float*)d_in[13];
    const float* We         = (const float*)d_in[14];
    const float* att        = (const float*)d_in[15];
    const float* gbias      = (const float*)d_in[16];
    const float* gn_w       = (const float*)d_in[17];
    const float* gn_b       = (const float*)d_in[18];
    const float* gn_ms      = (const float*)d_in[19];
    const float* lin_out_W  = (const float*)d_in[20];
    const float* lin_out_b  = (const float*)d_in[21];
    float* out = (float*)d_out;

    char* ws = (char*)d_ws;
    size_t off = 0;
    auto alloc = [&](size_t bytes)->void*{ void* p = ws + off; off += (bytes + 255) & ~(size_t)255; return p; };
    float* h     = (float*)alloc((size_t)NN*HIDC*4);
    bf16*  xl    = (bf16*) alloc((size_t)NN*HIDC*2);
    bf16*  xr    = (bf16*) alloc((size_t)NN*HIDC*2);
    bf16*  eWa   = (bf16*) alloc((size_t)NLAY*EVOC*HIDC*2);
    float* partial=(float*)alloc((size_t)GN_BLOCKS*2*HIDC*4);
    float* scale = (float*)alloc(HIDC*4);
    float* shift = (float*)alloc(HIDC*4);
    int* rowptr  = (int*)alloc((size_t)(NN+1)*4);
    int* cursor  = (int*)alloc((size_t)NN*4);
    int* src_p   = (int*)alloc((size_t)NE*4);
    int* code_p  = (int*)alloc((size_t)NE*4);
    float* ew_p  = (float*)alloc((size_t)NE*4);

    const int* src = edge_index;
    const int* dst = edge_index + NE;

    // CSR build (dst constant across layers -> built once per call)
    hipMemsetAsync(cursor, 0, (size_t)NN*4, stream);
    k_hist<<<(NE+255)/256, 256, 0, stream>>>(dst, cursor);
    k_scan<<<1, 1024, 0, stream>>>(cursor, rowptr);
    hipMemsetAsync(cursor, 0, (size_t)NN*4, stream);
    k_scatter<<<(NE+255)/256, 256, 0, stream>>>(src, dst, edge_code, edge_weight,
                                                rowptr, cursor, src_p, code_p, ew_p);

    // edge-vocab transform, all 6 layers in one launch: eWa[l] = edge_emb @ We[l]
    k_gemm<EDIM,HIDC,false,bf16><<<dim3((EVOC+63)/64, NLAY), 256, 0, stream>>>(
        edge_emb, We, nullptr, nullptr, nullptr, 0.f,
        eWa, EVOC, EDIM*HIDC, EVOC*HIDC);

    // lin_in -> h (fp32)
    k_gemm<FIN,HIDC,false,float><<<(NN+63)/64, 256, 0, stream>>>(
        x, lin_in_W, lin_in_b, nullptr, nullptr, 0.f, h, NN, 0, 0);

    // gn0 (no activation), in-place on h
    k_gn_reduce<<<GN_BLOCKS, 384, 0, stream>>>(h, partial);
    k_gn_finalize<<<1, 768, 0, stream>>>(partial, gn0_w, gn0_b, gn0_ms, scale, shift);
    k_gn_apply<<<768, 384, 0, stream>>>(h, scale, shift, h, 1.0f);

    for(int l=0;l<NLAY;l++){
        k_gn_reduce<<<GN_BLOCKS, 384, 0, stream>>>(h, partial);
        k_gn_finalize<<<1, 768, 0, stream>>>(partial, gn_w + l*HIDC, gn_b + l*HIDC, gn_ms + l*HIDC, scale, shift);
        // GN+LeakyReLU fused into A-tile stage; bf16 outputs
        k_gemm<HIDC,HIDC,true,bf16><<<(NN+63)/64, 256, 0, stream>>>(
            h, Wl + (size_t)l*HIDC*HIDC, bl + l*HIDC, scale, shift, ACT_SLOPE, xl, NN, 0, 0);
        k_gemm<HIDC,HIDC,true,bf16><<<(NN+63)/64, 256, 0, stream>>>(
            h, Wr + (size_t)l*HIDC*HIDC, br + l*HIDC, scale, shift, ACT_SLOPE, xr, NN, 0, 0);
        // fused logits + online softmax + aggregate + residual (wave per node)
        k_gat<<<(NN+3)/4, 256, 0, stream>>>(rowptr, src_p, code_p, ew_p, xl, xr,
                                            eWa + (size_t)l*EVOC*HIDC, att + l*NHEAD*HCH,
                                            gbias + l*HIDC, h);
    }

    // lin_out -> d_out (fp32)
    k_gemm<HIDC,FOUT,false,float><<<(NN+63)/64, 256, 0, stream>>>(
        h, lin_out_W, lin_out_b, nullptr, nullptr, 0.f, out, NN, 0, 0);
}

// Round 5
// 1025.780 us; speedup vs baseline: 2.4045x; 1.2069x over previous
//
#include <hip/hip_runtime.h>
#include <hip/hip_bf16.h>

// Problem constants
constexpr int NN   = 50000;   // nodes
constexpr int NE   = 800000;  // edges
constexpr int FIN  = 128;
constexpr int HIDC = 96;
constexpr int FOUT = 64;
constexpr int NHEAD= 8;
constexpr int HCH  = 12;
constexpr int NLAY = 6;
constexpr int EVOC = 1000;
constexpr int EDIM = 32;
constexpr float ACT_SLOPE = 0.01f;
constexpr float ATT_SLOPE = 0.2f;
constexpr float GN_EPS = 1e-5f;
constexpr int GN_BLOCKS = 256;
constexpr int NSCB = (NN + 255)/256;   // scan blocks (196)

typedef __hip_bfloat16 bf16;

__device__ __forceinline__ float bfu(unsigned u, int hi){
    return __uint_as_float(hi ? (u & 0xffff0000u) : (u << 16));
}
__device__ __forceinline__ unsigned pkbf(float a, float b){
    bf16 x = __float2bfloat16(a), y = __float2bfloat16(b);
    unsigned short ux = *(unsigned short*)&x, uy = *(unsigned short*)&y;
    return (unsigned)ux | ((unsigned)uy << 16);
}

// ---------------- CSR build ----------------
__global__ void k_hist(const int* __restrict__ dst, int* __restrict__ deg){
    int e = blockIdx.x*blockDim.x + threadIdx.x;
    if(e < NE) atomicAdd(&deg[dst[e]], 1);
}

// 3-phase parallel exclusive scan of deg[NN] -> rowptr[NN+1]
__global__ __launch_bounds__(256) void k_scan1(const int* __restrict__ deg,
        int* __restrict__ pre, int* __restrict__ bsum){
    __shared__ int s[256];
    int tid = threadIdx.x;
    int idx = blockIdx.x*256 + tid;
    int v = (idx < NN) ? deg[idx] : 0;
    s[tid] = v; __syncthreads();
    #pragma unroll
    for(int off=1; off<256; off<<=1){
        int t = (tid>=off) ? s[tid-off] : 0;
        __syncthreads();
        s[tid] += t;
        __syncthreads();
    }
    if(idx < NN) pre[idx] = s[tid] - v;          // exclusive
    if(tid == 255) bsum[blockIdx.x] = s[255];    // block total
}

__global__ __launch_bounds__(256) void k_scan2(const int* __restrict__ bsum,
        int* __restrict__ boffs){
    __shared__ int s[256];
    int tid = threadIdx.x;
    int v = (tid < NSCB) ? bsum[tid] : 0;
    s[tid] = v; __syncthreads();
    #pragma unroll
    for(int off=1; off<256; off<<=1){
        int t = (tid>=off) ? s[tid-off] : 0;
        __syncthreads();
        s[tid] += t;
        __syncthreads();
    }
    if(tid < NSCB) boffs[tid] = s[tid] - v;      // exclusive
}

__global__ __launch_bounds__(256) void k_scan3(const int* __restrict__ pre,
        const int* __restrict__ boffs, int* __restrict__ rowptr){
    int tid = threadIdx.x;
    int idx = blockIdx.x*256 + tid;
    if(idx < NN) rowptr[idx] = pre[idx] + boffs[blockIdx.x];
    if(blockIdx.x == 0 && tid == 0) rowptr[NN] = NE;
}

__global__ void k_scatter(const int* __restrict__ src, const int* __restrict__ dst,
                          const int* __restrict__ code, const float* __restrict__ ew,
                          const int* __restrict__ rowptr, int* __restrict__ cursor,
                          int4* __restrict__ epk){
    int e = blockIdx.x*blockDim.x + threadIdx.x;
    if(e >= NE) return;
    int d = dst[e];
    int pos = rowptr[d] + atomicAdd(&cursor[d], 1);
    epk[pos] = make_int4(src[e], code[e], __float_as_int(ew[e]), 0);
}

// -------- small GEMM: C[M,NC] = f(A[M,K])@W[K,NC] + bias (generic, minor uses) --------
template<int K, int NC, bool GN, typename OT>
__global__ __launch_bounds__(256) void k_gemm(const float* __restrict__ A,
        const float* __restrict__ W, const float* __restrict__ bias,
        const float* __restrict__ gscale, const float* __restrict__ gshift, float slope,
        OT* __restrict__ C, int M, int wstride, int cstride){
    constexpr int CPT = NC/16;   // cols per thread (96->6, 64->4)
    W += (size_t)blockIdx.y * wstride;
    C += (size_t)blockIdx.y * cstride;
    __shared__ float At[K][68];  // transposed A tile (64 rows), padded
    int tid = threadIdx.x;
    int m0 = blockIdx.x*64;
    for(int i=tid; i<64*K; i+=256){
        int r = i / K, k = i - r*K;
        int row = m0 + r;
        float v = (row < M) ? A[(size_t)row*K + k] : 0.f;
        if constexpr (GN){
            v = gscale[k]*v + gshift[k];
            v = (v > 0.f) ? v : slope*v;
        }
        At[k][r] = v;
    }
    __syncthreads();
    int tr = tid>>4, tc = tid&15;
    const float* wr = W + tc*CPT;
    float acc[4][CPT];
    #pragma unroll
    for(int i=0;i<4;i++)
        #pragma unroll
        for(int j=0;j<CPT;j++) acc[i][j]=0.f;
    #pragma unroll 4
    for(int k=0;k<K;k++){
        float a[4], w[CPT];
        #pragma unroll
        for(int i=0;i<4;i++) a[i] = At[k][tr*4+i];
        #pragma unroll
        for(int j=0;j<CPT;j++) w[j] = wr[k*NC + j];
        #pragma unroll
        for(int i=0;i<4;i++)
            #pragma unroll
            for(int j=0;j<CPT;j++) acc[i][j] += a[i]*w[j];
    }
    #pragma unroll
    for(int i=0;i<4;i++){
        int row = m0 + tr*4 + i;
        if(row < M){
            OT* cp = C + (size_t)row*NC + tc*CPT;
            #pragma unroll
            for(int j=0;j<CPT;j++){
                float v = acc[i][j] + (bias ? bias[tc*CPT+j] : 0.f);
                if constexpr (sizeof(OT)==2) cp[j] = __float2bfloat16(v);
                else cp[j] = v;
            }
        }
    }
}

// -------- fused dual GEMM: xl = f(A)@W1+b1, xr = f(A)@W2+b2, f = GN+LeakyReLU --------
// A staged once (float4 loads), two weight streams via L1/L2, bf16-packed stores.
template<int K>
__global__ __launch_bounds__(256) void k_gemm2(const float* __restrict__ A,
        const float* __restrict__ W1, const float* __restrict__ b1,
        const float* __restrict__ W2, const float* __restrict__ b2,
        const float* __restrict__ gscale, const float* __restrict__ gshift, float slope,
        bf16* __restrict__ C1, bf16* __restrict__ C2, int M){
    constexpr int NC = 96, CPT = 6, KQ = K/4;
    __shared__ float At[K][68];
    int tid = threadIdx.x;
    int m0 = blockIdx.x*64;
    for(int j=tid; j<64*KQ; j+=256){
        int r = j / KQ, kq = j - r*KQ;
        int row = m0 + r;
        float4 v = (row < M) ? ((const float4*)A)[(size_t)row*KQ + kq]
                             : make_float4(0.f,0.f,0.f,0.f);
        float vv[4] = {v.x, v.y, v.z, v.w};
        #pragma unroll
        for(int c=0;c<4;c++){
            int k = kq*4 + c;
            float u = gscale[k]*vv[c] + gshift[k];
            u = (u > 0.f) ? u : slope*u;
            At[k][r] = u;
        }
    }
    __syncthreads();
    int tr = tid>>4, tc = tid&15;
    const float2* w1 = (const float2*)(W1 + tc*CPT);
    const float2* w2 = (const float2*)(W2 + tc*CPT);
    float acc1[4][CPT], acc2[4][CPT];
    #pragma unroll
    for(int i=0;i<4;i++)
        #pragma unroll
        for(int j=0;j<CPT;j++){ acc1[i][j]=0.f; acc2[i][j]=0.f; }
    #pragma unroll 2
    for(int k=0;k<K;k++){
        float a[4];
        #pragma unroll
        for(int i=0;i<4;i++) a[i] = At[k][tr*4+i];
        float2 x0=w1[k*48+0], x1=w1[k*48+1], x2=w1[k*48+2];
        float2 y0=w2[k*48+0], y1=w2[k*48+1], y2=w2[k*48+2];
        float wv1[CPT] = {x0.x,x0.y,x1.x,x1.y,x2.x,x2.y};
        float wv2[CPT] = {y0.x,y0.y,y1.x,y1.y,y2.x,y2.y};
        #pragma unroll
        for(int i=0;i<4;i++){
            #pragma unroll
            for(int j=0;j<CPT;j++){
                acc1[i][j] += a[i]*wv1[j];
                acc2[i][j] += a[i]*wv2[j];
            }
        }
    }
    float bb1[CPT], bb2[CPT];
    #pragma unroll
    for(int j=0;j<CPT;j++){ bb1[j]=b1[tc*CPT+j]; bb2[j]=b2[tc*CPT+j]; }
    #pragma unroll
    for(int i=0;i<4;i++){
        int row = m0 + tr*4 + i;
        if(row < M){
            unsigned* o1 = (unsigned*)(C1 + (size_t)row*NC + tc*CPT);
            unsigned* o2 = (unsigned*)(C2 + (size_t)row*NC + tc*CPT);
            #pragma unroll
            for(int q=0;q<3;q++){
                o1[q] = pkbf(acc1[i][2*q]+bb1[2*q], acc1[i][2*q+1]+bb1[2*q+1]);
                o2[q] = pkbf(acc2[i][2*q]+bb2[2*q], acc2[i][2*q+1]+bb2[2*q+1]);
            }
        }
    }
}

// ---------------- GraphNorm stats ----------------
__global__ __launch_bounds__(384) void k_gn_reduce(const float* __restrict__ x, float* __restrict__ partial){
    int tid = threadIdx.x;
    float s=0.f, s2=0.f;
    const int total = NN*HIDC;
    const int stride = GN_BLOCKS*384;
    for(int i=blockIdx.x*384+tid; i<total; i+=stride){
        float v = x[i];
        s += v; s2 += v*v;
    }
    __shared__ float ls[384], ls2[384];
    ls[tid]=s; ls2[tid]=s2;
    __syncthreads();
    if(tid < HIDC){
        float a  = ls[tid]+ls[tid+96]+ls[tid+192]+ls[tid+288];
        float b2 = ls2[tid]+ls2[tid+96]+ls2[tid+192]+ls2[tid+288];
        partial[blockIdx.x*192 + tid]      = a;
        partial[blockIdx.x*192 + 96 + tid] = b2;
    }
}

__global__ __launch_bounds__(768) void k_gn_finalize(const float* __restrict__ partial,
        const float* __restrict__ w, const float* __restrict__ b, const float* __restrict__ ms,
        float* __restrict__ scale, float* __restrict__ shift){
    __shared__ float red[4][192];
    int tid = threadIdx.x;
    int v = tid % 192, seg = tid / 192;   // 4 segments
    float s = 0.f;
    #pragma unroll 8
    for(int bk=seg; bk<GN_BLOCKS; bk+=4) s += partial[bk*192 + v];
    red[seg][v] = s;
    __syncthreads();
    if(tid < 192) red[0][tid] = red[0][tid]+red[1][tid]+red[2][tid]+red[3][tid];
    __syncthreads();
    if(tid < HIDC){
        float mean = red[0][tid] / (float)NN;
        float m2   = red[0][tid+96] / (float)NN;
        float mm   = ms[tid]*mean;
        float var  = m2 - 2.f*mm*mean + mm*mm;
        float sc   = w[tid] * rsqrtf(var + GN_EPS);
        scale[tid] = sc;
        shift[tid] = b[tid] - sc*mm;
    }
}

__global__ __launch_bounds__(384) void k_gn_apply(const float* __restrict__ x,
        const float* __restrict__ scale, const float* __restrict__ shift,
        float* __restrict__ out, float slope){
    int tid = threadIdx.x;
    int c = tid % HIDC;
    float sc = scale[c], sh = shift[c];
    const int total = NN*HIDC;
    const int stride = gridDim.x*384;
    for(int i=blockIdx.x*384+tid; i<total; i+=stride){
        float v = sc*x[i] + sh;
        out[i] = (v > 0.f) ? v : slope*v;
    }
}

// ---- fully fused GATv2 edge path, wave-per-node, barrier-free ----
__global__ __launch_bounds__(256) void k_gat(const int* __restrict__ rowptr,
        const int4* __restrict__ epk,
        const bf16* __restrict__ xl, const bf16* __restrict__ xr,
        const bf16* __restrict__ eW, const float* __restrict__ att_l,
        const float* __restrict__ gbias_l, float* __restrict__ h){
    int wid  = threadIdx.x >> 6;
    int lane = threadIdx.x & 63;
    int n = blockIdx.x*4 + wid;
    __shared__ bf16  xls[4][8][104];   // padded
    __shared__ float pl[4][8][NHEAD];
    __shared__ float sS[4][NHEAD];
    __shared__ float zS[4][NHEAD];
    if(n >= NN) return;
    int r0 = rowptr[n], r1 = rowptr[n+1];
    int e_loc = lane >> 3, hh = lane & 7;
    // hoisted per-lane invariants: xr chunk + att chunk for head hh
    float xrh[HCH], ath[HCH];
    {
        const uint2* x2 = (const uint2*)(xr + (size_t)n*HIDC + hh*HCH);
        #pragma unroll
        for(int q=0;q<3;q++){
            uint2 u = x2[q];
            xrh[q*4+0]=bfu(u.x,0); xrh[q*4+1]=bfu(u.x,1);
            xrh[q*4+2]=bfu(u.y,0); xrh[q*4+3]=bfu(u.y,1);
        }
        const float4* a4 = (const float4*)(att_l + hh*HCH);
        #pragma unroll
        for(int q=0;q<3;q++){
            float4 f = a4[q];
            ath[q*4+0]=f.x; ath[q*4+1]=f.y; ath[q*4+2]=f.z; ath[q*4+3]=f.w;
        }
    }
    float m = -3.0e38f, z = 0.f;
    float acc0 = 0.f, acc1 = 0.f;
    const int c0 = lane;               // channel for all lanes
    const int c1 = 64 + (lane & 31);   // extra channel for lanes < 32
    const int hd0 = c0 / HCH;
    const int hd1 = c1 / HCH;
    for(int base = r0; base < r1; base += 8){
        int eidx = base + e_loc;
        float lg = -3.0e38f, ew = 0.f;
        uint2 stv[3]; uint2 ebv[3];
        #pragma unroll
        for(int q=0;q<3;q++){ stv[q] = make_uint2(0u,0u); ebv[q] = stv[q]; }
        if(eidx < r1){
            int4 ec = epk[eidx];
            int s  = ec.x;
            int cd = ec.y;
            ew = __int_as_float(ec.z);
            const uint2* xa = (const uint2*)(xl + (size_t)s*HIDC + hh*HCH);
            const uint2* eb = (const uint2*)(eW + (size_t)cd*HIDC + hh*HCH);
            #pragma unroll
            for(int q=0;q<3;q++){ stv[q] = xa[q]; ebv[q] = eb[q]; }
            float dot = 0.f;
            #pragma unroll
            for(int q=0;q<3;q++){
                unsigned ux[2] = {stv[q].x, stv[q].y};
                unsigned ue[2] = {ebv[q].x, ebv[q].y};
                #pragma unroll
                for(int k2=0;k2<4;k2++){
                    float v = bfu(ux[k2>>1], k2&1) + xrh[q*4+k2] + bfu(ue[k2>>1], k2&1);
                    v = (v > 0.f) ? v : ATT_SLOPE*v;
                    dot += v * ath[q*4+k2];
                }
            }
            lg = dot;
        }
        // stage xl chunk (zeros for invalid edges)
        uint2* d2 = (uint2*)(&xls[wid][e_loc][hh*HCH]);
        d2[0]=stv[0]; d2[1]=stv[1]; d2[2]=stv[2];
        // online softmax update, per head (reduce over e-bits = lane bits 3..5)
        float tm = lg;
        tm = fmaxf(tm, __shfl_xor(tm, 8));
        tm = fmaxf(tm, __shfl_xor(tm, 16));
        tm = fmaxf(tm, __shfl_xor(tm, 32));
        float mn = fmaxf(m, tm);
        float sc = __expf(m - mn);      // first tile: exp(-3e38) = 0
        float p  = __expf(lg - mn);     // invalid lanes: 0
        float zt = p;
        zt += __shfl_xor(zt, 8); zt += __shfl_xor(zt, 16); zt += __shfl_xor(zt, 32);
        z = z*sc + zt;
        m = mn;
        pl[wid][e_loc][hh] = p * ew;
        if(lane < NHEAD) sS[wid][lane] = sc;   // lanes 0..7: e_loc=0, hh=lane
        __builtin_amdgcn_wave_barrier();
        asm volatile("" ::: "memory");
        // aggregate this tile (all lanes busy; lanes<32 carry a 2nd channel)
        float s0 = sS[wid][hd0];
        float a0 = 0.f;
        #pragma unroll
        for(int e=0;e<8;e++)
            a0 += pl[wid][e][hd0] * __bfloat162float(xls[wid][e][c0]);
        acc0 = acc0*s0 + a0;
        if(lane < 32){
            float s1 = sS[wid][hd1];
            float a1 = 0.f;
            #pragma unroll
            for(int e=0;e<8;e++)
                a1 += pl[wid][e][hd1] * __bfloat162float(xls[wid][e][c1]);
            acc1 = acc1*s1 + a1;
        }
        asm volatile("" ::: "memory");
        __builtin_amdgcn_wave_barrier();
    }
    if(lane < NHEAD) zS[wid][lane] = z;
    __builtin_amdgcn_wave_barrier();
    asm volatile("" ::: "memory");
    float z0 = zS[wid][hd0];
    h[(size_t)n*HIDC + c0] += acc0/(z0 + 1e-16f) + gbias_l[c0];
    if(lane < 32){
        float z1 = zS[wid][hd1];
        h[(size_t)n*HIDC + c1] += acc1/(z1 + 1e-16f) + gbias_l[c1];
    }
}

// ---------------- launch ----------------
extern "C" void kernel_launch(void* const* d_in, const int* in_sizes, int n_in,
                              void* d_out, int out_size, void* d_ws, size_t ws_size,
                              hipStream_t stream) {
    (void)in_sizes; (void)n_in; (void)out_size; (void)ws_size;
    const float* x          = (const float*)d_in[0];
    const int*   edge_index = (const int*)  d_in[1];
    const float* edge_weight= (const float*)d_in[2];
    const int*   edge_code  = (const int*)  d_in[3];
    const float* edge_emb   = (const float*)d_in[4];
    const float* lin_in_W   = (const float*)d_in[5];
    const float* lin_in_b   = (const float*)d_in[6];
    const float* gn0_w      = (const float*)d_in[7];
    const float* gn0_b      = (const float*)d_in[8];
    const float* gn0_ms     = (const float*)d_in[9];
    const float* Wl         = (const float*)d_in[10];
    const float* bl         = (const float*)d_in[11];
    const float* Wr         = (const float*)d_in[12];
    const float* br         = (const float*)d_in[13];
    const float* We         = (const float*)d_in[14];
    const float* att        = (const float*)d_in[15];
    const float* gbias      = (const float*)d_in[16];
    const float* gn_w       = (const float*)d_in[17];
    const float* gn_b       = (const float*)d_in[18];
    const float* gn_ms      = (const float*)d_in[19];
    const float* lin_out_W  = (const float*)d_in[20];
    const float* lin_out_b  = (const float*)d_in[21];
    float* out = (float*)d_out;

    char* ws = (char*)d_ws;
    size_t off = 0;
    auto alloc = [&](size_t bytes)->void*{ void* p = ws + off; off += (bytes + 255) & ~(size_t)255; return p; };
    float* h     = (float*)alloc((size_t)NN*HIDC*4);
    bf16*  xl    = (bf16*) alloc((size_t)NN*HIDC*2);
    bf16*  xr    = (bf16*) alloc((size_t)NN*HIDC*2);
    bf16*  eWa   = (bf16*) alloc((size_t)NLAY*EVOC*HIDC*2);
    float* partial=(float*)alloc((size_t)GN_BLOCKS*2*HIDC*4);
    float* scale = (float*)alloc(HIDC*4);
    float* shift = (float*)alloc(HIDC*4);
    int* rowptr  = (int*)alloc((size_t)(NN+1)*4);
    int* cursor  = (int*)alloc((size_t)NN*4);
    int* pre     = (int*)alloc((size_t)NN*4);
    int* bsum    = (int*)alloc((size_t)NSCB*4);
    int* boffs   = (int*)alloc((size_t)NSCB*4);
    int4* epk    = (int4*)alloc((size_t)NE*16);

    const int* src = edge_index;
    const int* dst = edge_index + NE;

    // CSR build (dst constant across layers -> built once per call)
    hipMemsetAsync(cursor, 0, (size_t)NN*4, stream);
    k_hist<<<(NE+255)/256, 256, 0, stream>>>(dst, cursor);
    k_scan1<<<NSCB, 256, 0, stream>>>(cursor, pre, bsum);
    k_scan2<<<1, 256, 0, stream>>>(bsum, boffs);
    k_scan3<<<NSCB, 256, 0, stream>>>(pre, boffs, rowptr);
    hipMemsetAsync(cursor, 0, (size_t)NN*4, stream);
    k_scatter<<<(NE+255)/256, 256, 0, stream>>>(src, dst, edge_code, edge_weight,
                                                rowptr, cursor, epk);

    // edge-vocab transform, all 6 layers in one launch: eWa[l] = edge_emb @ We[l]
    k_gemm<EDIM,HIDC,false,bf16><<<dim3((EVOC+63)/64, NLAY), 256, 0, stream>>>(
        edge_emb, We, nullptr, nullptr, nullptr, 0.f,
        eWa, EVOC, EDIM*HIDC, EVOC*HIDC);

    // lin_in -> h (fp32)
    k_gemm<FIN,HIDC,false,float><<<(NN+63)/64, 256, 0, stream>>>(
        x, lin_in_W, lin_in_b, nullptr, nullptr, 0.f, h, NN, 0, 0);

    // gn0 (no activation), in-place on h
    k_gn_reduce<<<GN_BLOCKS, 384, 0, stream>>>(h, partial);
    k_gn_finalize<<<1, 768, 0, stream>>>(partial, gn0_w, gn0_b, gn0_ms, scale, shift);
    k_gn_apply<<<768, 384, 0, stream>>>(h, scale, shift, h, 1.0f);

    for(int l=0;l<NLAY;l++){
        k_gn_reduce<<<GN_BLOCKS, 384, 0, stream>>>(h, partial);
        k_gn_finalize<<<1, 768, 0, stream>>>(partial, gn_w + l*HIDC, gn_b + l*HIDC, gn_ms + l*HIDC, scale, shift);
        // fused dual GEMM: GN+LeakyReLU in A-stage, xl & xr in one pass
        k_gemm2<HIDC><<<(NN+63)/64, 256, 0, stream>>>(
            h, Wl + (size_t)l*HIDC*HIDC, bl + l*HIDC,
               Wr + (size_t)l*HIDC*HIDC, br + l*HIDC,
            scale, shift, ACT_SLOPE, xl, xr, NN);
        // fused logits + online softmax + aggregate + residual (wave per node)
        k_gat<<<(NN+3)/4, 256, 0, stream>>>(rowptr, epk, xl, xr,
                                            eWa + (size_t)l*EVOC*HIDC, att + l*NHEAD*HCH,
                                            gbias + l*HIDC, h);
    }

    // lin_out -> d_out (fp32)
    k_gemm<HIDC,FOUT,false,float><<<(NN+63)/64, 256, 0, stream>>>(
        h, lin_out_W, lin_out_b, nullptr, nullptr, 0.f, out, NN, 0, 0);
}

// Round 6
// 774.398 us; speedup vs baseline: 3.1851x; 1.3246x over previous
//
#include <hip/hip_runtime.h>
#include <hip/hip_bf16.h>

// Problem constants
constexpr int NN   = 50000;   // nodes
constexpr int NE   = 800000;  // edges
constexpr int FIN  = 128;
constexpr int HIDC = 96;
constexpr int FOUT = 64;
constexpr int NHEAD= 8;
constexpr int HCH  = 12;
constexpr int NLAY = 6;
constexpr int EVOC = 1000;
constexpr int EDIM = 32;
constexpr float ACT_SLOPE = 0.01f;
constexpr float ATT_SLOPE = 0.2f;
constexpr float GN_EPS = 1e-5f;
constexpr int GN_BLOCKS = 256;
constexpr int NSCB = (NN + 255)/256;   // scan blocks (196)

typedef __hip_bfloat16 bf16;
typedef __attribute__((ext_vector_type(8))) short bf16x8;
typedef __attribute__((ext_vector_type(4))) float f32x4;

__device__ __forceinline__ float bfu(unsigned u, int hi){
    return __uint_as_float(hi ? (u & 0xffff0000u) : (u << 16));
}

// ---------------- CSR build ----------------
__global__ void k_hist(const int* __restrict__ dst, int* __restrict__ deg){
    int e = blockIdx.x*blockDim.x + threadIdx.x;
    if(e < NE) atomicAdd(&deg[dst[e]], 1);
}

__global__ __launch_bounds__(256) void k_scan1(const int* __restrict__ deg,
        int* __restrict__ pre, int* __restrict__ bsum){
    __shared__ int s[256];
    int tid = threadIdx.x;
    int idx = blockIdx.x*256 + tid;
    int v = (idx < NN) ? deg[idx] : 0;
    s[tid] = v; __syncthreads();
    #pragma unroll
    for(int off=1; off<256; off<<=1){
        int t = (tid>=off) ? s[tid-off] : 0;
        __syncthreads();
        s[tid] += t;
        __syncthreads();
    }
    if(idx < NN) pre[idx] = s[tid] - v;          // exclusive
    if(tid == 255) bsum[blockIdx.x] = s[255];    // block total
}

__global__ __launch_bounds__(256) void k_scan2(const int* __restrict__ bsum,
        int* __restrict__ boffs){
    __shared__ int s[256];
    int tid = threadIdx.x;
    int v = (tid < NSCB) ? bsum[tid] : 0;
    s[tid] = v; __syncthreads();
    #pragma unroll
    for(int off=1; off<256; off<<=1){
        int t = (tid>=off) ? s[tid-off] : 0;
        __syncthreads();
        s[tid] += t;
        __syncthreads();
    }
    if(tid < NSCB) boffs[tid] = s[tid] - v;      // exclusive
}

__global__ __launch_bounds__(256) void k_scan3(const int* __restrict__ pre,
        const int* __restrict__ boffs, int* __restrict__ rowptr){
    int tid = threadIdx.x;
    int idx = blockIdx.x*256 + tid;
    if(idx < NN) rowptr[idx] = pre[idx] + boffs[blockIdx.x];
    if(blockIdx.x == 0 && tid == 0) rowptr[NN] = NE;
}

__global__ void k_scatter(const int* __restrict__ src, const int* __restrict__ dst,
                          const int* __restrict__ code, const float* __restrict__ ew,
                          const int* __restrict__ rowptr, int* __restrict__ cursor,
                          int4* __restrict__ epk){
    int e = blockIdx.x*blockDim.x + threadIdx.x;
    if(e >= NE) return;
    int d = dst[e];
    int pos = rowptr[d] + atomicAdd(&cursor[d], 1);
    epk[pos] = make_int4(src[e], code[e], __float_as_int(ew[e]), 0);
}

// ---------------- weight transpose + bf16 pack: Wt[n][k] = W[k][n] ----------------
__global__ __launch_bounds__(256) void k_tr(const float* __restrict__ W, bf16* __restrict__ Wt,
                                            int K, int N){
    int mat = blockIdx.y;
    W  += (size_t)mat*K*N;
    Wt += (size_t)mat*K*N;
    int i = blockIdx.x*256 + threadIdx.x;
    if(i >= K*N) return;
    int k = i / N, nn = i - k*N;
    Wt[(size_t)nn*K + k] = __float2bfloat16(W[i]);
}

// -------- small GEMM (fp32 VALU, minor uses: eWa, lin_out) --------
template<int K, int NC, typename OT>
__global__ __launch_bounds__(256) void k_gemm(const float* __restrict__ A,
        const float* __restrict__ W, const float* __restrict__ bias,
        OT* __restrict__ C, int M, int wstride, int cstride){
    constexpr int CPT = NC/16;
    W += (size_t)blockIdx.y * wstride;
    C += (size_t)blockIdx.y * cstride;
    __shared__ float At[K][68];
    int tid = threadIdx.x;
    int m0 = blockIdx.x*64;
    for(int i=tid; i<64*K; i+=256){
        int r = i / K, k = i - r*K;
        int row = m0 + r;
        At[k][r] = (row < M) ? A[(size_t)row*K + k] : 0.f;
    }
    __syncthreads();
    int tr = tid>>4, tc = tid&15;
    const float* wr = W + tc*CPT;
    float acc[4][CPT];
    #pragma unroll
    for(int i=0;i<4;i++)
        #pragma unroll
        for(int j=0;j<CPT;j++) acc[i][j]=0.f;
    #pragma unroll 4
    for(int k=0;k<K;k++){
        float a[4], w[CPT];
        #pragma unroll
        for(int i=0;i<4;i++) a[i] = At[k][tr*4+i];
        #pragma unroll
        for(int j=0;j<CPT;j++) w[j] = wr[k*NC + j];
        #pragma unroll
        for(int i=0;i<4;i++)
            #pragma unroll
            for(int j=0;j<CPT;j++) acc[i][j] += a[i]*w[j];
    }
    #pragma unroll
    for(int i=0;i<4;i++){
        int row = m0 + tr*4 + i;
        if(row < M){
            OT* cp = C + (size_t)row*NC + tc*CPT;
            #pragma unroll
            for(int j=0;j<CPT;j++){
                float v = acc[i][j] + (bias ? bias[tc*CPT+j] : 0.f);
                if constexpr (sizeof(OT)==2) cp[j] = __float2bfloat16(v);
                else cp[j] = v;
            }
        }
    }
}

// -------- MFMA GEMM: C[M,96] = f(A[M,K]) @ W (optionally dual W), f = GN+LeakyReLU --------
// W passed pre-transposed bf16: Wt[n][k]. A staged to LDS as bf16 (GN applied).
// Fragment maps (m89-verified): A: row=l&15, k=(l>>4)*8+j ; B: col=l&15, same k ;
// C/D: col=l&15, row=(l>>4)*4+reg.
template<int K, bool GN, bool DUAL, typename OT>
__global__ __launch_bounds__(256) void k_mfgemm(const float* __restrict__ A,
        const bf16* __restrict__ W1t, const float* __restrict__ b1,
        const bf16* __restrict__ W2t, const float* __restrict__ b2,
        const float* __restrict__ gscale, const float* __restrict__ gshift, float slope,
        OT* __restrict__ C1, OT* __restrict__ C2, int M){
    constexpr int KP = K + 8;            // row pad: 104 / 136 (keeps b128 reads 2-way)
    constexpr int F4R = K/4;
    constexpr int NF4 = 64*F4R;
    constexpr int KS = K/32;
    __shared__ bf16 At[64][KP];
    int tid = threadIdx.x;
    int m0 = blockIdx.x*64;
    for(int idx = tid; idx < NF4; idx += 256){
        int r = idx / F4R, c4 = idx - r*F4R;
        int row = m0 + r;
        float4 v = (row < M) ? ((const float4*)A)[(size_t)row*F4R + c4]
                             : make_float4(0.f,0.f,0.f,0.f);
        float vv[4] = {v.x, v.y, v.z, v.w};
        bf16* dp = &At[r][c4*4];
        #pragma unroll
        for(int c=0;c<4;c++){
            float u = vv[c];
            if constexpr (GN){
                int k = c4*4 + c;
                u = gscale[k]*u + gshift[k];
                u = (u > 0.f) ? u : slope*u;
            }
            dp[c] = __float2bfloat16(u);
        }
    }
    __syncthreads();
    int w = tid >> 6, l = tid & 63;
    int mrow = l & 15;
    int kg = (l >> 4) * 8;
    f32x4 acc1[6], acc2[6];
    #pragma unroll
    for(int nt=0; nt<6; nt++){
        acc1[nt] = (f32x4){0.f,0.f,0.f,0.f};
        if constexpr (DUAL) acc2[nt] = (f32x4){0.f,0.f,0.f,0.f};
    }
    const bf16* a_base = &At[w*16 + mrow][0];
    #pragma unroll
    for(int ks=0; ks<KS; ks++){
        bf16x8 a = *(const bf16x8*)(a_base + ks*32 + kg);
        #pragma unroll
        for(int nt=0; nt<6; nt++){
            int n = nt*16 + mrow;
            bf16x8 bfr = *(const bf16x8*)(W1t + (size_t)n*K + ks*32 + kg);
            acc1[nt] = __builtin_amdgcn_mfma_f32_16x16x32_bf16(a, bfr, acc1[nt], 0,0,0);
            if constexpr (DUAL){
                bf16x8 bfr2 = *(const bf16x8*)(W2t + (size_t)n*K + ks*32 + kg);
                acc2[nt] = __builtin_amdgcn_mfma_f32_16x16x32_bf16(a, bfr2, acc2[nt], 0,0,0);
            }
        }
    }
    int rbase = m0 + w*16 + (l>>4)*4;
    #pragma unroll
    for(int nt=0; nt<6; nt++){
        int n = nt*16 + mrow;
        float bb1 = b1[n];
        float bb2 = 0.f;
        if constexpr (DUAL) bb2 = b2[n];
        #pragma unroll
        for(int r=0;r<4;r++){
            int row = rbase + r;
            if(row < M){
                float v1 = acc1[nt][r] + bb1;
                if constexpr (sizeof(OT)==2) C1[(size_t)row*96 + n] = __float2bfloat16(v1);
                else                         C1[(size_t)row*96 + n] = v1;
                if constexpr (DUAL){
                    float v2 = acc2[nt][r] + bb2;
                    C2[(size_t)row*96 + n] = __float2bfloat16(v2);
                }
            }
        }
    }
}

// ---------------- GraphNorm stats (float4 loads) ----------------
__global__ __launch_bounds__(384) void k_gn_reduce(const float* __restrict__ x, float* __restrict__ partial){
    int tid = threadIdx.x;
    const float4* x4 = (const float4*)x;
    constexpr int TOT4 = NN*HIDC/4;
    const int stride = GN_BLOCKS*384;
    float s0=0,s1=0,s2=0,s3=0, q0=0,q1=0,q2=0,q3=0;
    for(int i = blockIdx.x*384 + tid; i < TOT4; i += stride){
        float4 v = x4[i];
        s0+=v.x; q0+=v.x*v.x;
        s1+=v.y; q1+=v.y*v.y;
        s2+=v.z; q2+=v.z*v.z;
        s3+=v.w; q3+=v.w*v.w;
    }
    __shared__ float ls[384][4], lq[384][4];
    ls[tid][0]=s0; ls[tid][1]=s1; ls[tid][2]=s2; ls[tid][3]=s3;
    lq[tid][0]=q0; lq[tid][1]=q1; lq[tid][2]=q2; lq[tid][3]=q3;
    __syncthreads();
    // thread's float4 index i ≡ tid (mod 24) -> channel group g=tid%24 covers channels 4g..4g+3
    if(tid < 96){
        int g = tid >> 2, c = tid & 3;   // g < 24
        float a=0.f, b=0.f;
        #pragma unroll
        for(int j=0;j<16;j++){
            a += ls[g + 24*j][c];
            b += lq[g + 24*j][c];
        }
        partial[blockIdx.x*192 + g*4 + c]      = a;
        partial[blockIdx.x*192 + 96 + g*4 + c] = b;
    }
}

__global__ __launch_bounds__(768) void k_gn_finalize(const float* __restrict__ partial,
        const float* __restrict__ w, const float* __restrict__ b, const float* __restrict__ ms,
        float* __restrict__ scale, float* __restrict__ shift){
    __shared__ float red[4][192];
    int tid = threadIdx.x;
    int v = tid % 192, seg = tid / 192;
    float s = 0.f;
    #pragma unroll 8
    for(int bk=seg; bk<GN_BLOCKS; bk+=4) s += partial[bk*192 + v];
    red[seg][v] = s;
    __syncthreads();
    if(tid < 192) red[0][tid] = red[0][tid]+red[1][tid]+red[2][tid]+red[3][tid];
    __syncthreads();
    if(tid < HIDC){
        float mean = red[0][tid] / (float)NN;
        float m2   = red[0][tid+96] / (float)NN;
        float mm   = ms[tid]*mean;
        float var  = m2 - 2.f*mm*mean + mm*mm;
        float sc   = w[tid] * rsqrtf(var + GN_EPS);
        scale[tid] = sc;
        shift[tid] = b[tid] - sc*mm;
    }
}

__global__ __launch_bounds__(384) void k_gn_apply(const float* __restrict__ x,
        const float* __restrict__ scale, const float* __restrict__ shift,
        float* __restrict__ out, float slope){
    int tid = threadIdx.x;
    int c = tid % HIDC;
    float sc = scale[c], sh = shift[c];
    const int total = NN*HIDC;
    const int stride = gridDim.x*384;
    for(int i=blockIdx.x*384+tid; i<total; i+=stride){
        float v = sc*x[i] + sh;
        out[i] = (v > 0.f) ? v : slope*v;
    }
}

// ---- fused GATv2 edge path, wave-per-node, 2-deep prefetch pipeline ----
__global__ __launch_bounds__(256) void k_gat(const int* __restrict__ rowptr,
        const int4* __restrict__ epk,
        const bf16* __restrict__ xl, const bf16* __restrict__ xr,
        const bf16* __restrict__ eW, const float* __restrict__ att_l,
        const float* __restrict__ gbias_l, float* __restrict__ h){
    int wid  = threadIdx.x >> 6;
    int lane = threadIdx.x & 63;
    int n = blockIdx.x*4 + wid;
    __shared__ bf16  xls[4][8][104];
    __shared__ float pl[4][8][NHEAD];
    __shared__ float sS[4][NHEAD];
    __shared__ float zS[4][NHEAD];
    if(n >= NN) return;
    int r0 = rowptr[n], r1 = rowptr[n+1];
    int e_loc = lane >> 3, hh = lane & 7;
    float xrh[HCH], ath[HCH];
    {
        const uint2* x2 = (const uint2*)(xr + (size_t)n*HIDC + hh*HCH);
        #pragma unroll
        for(int q=0;q<3;q++){
            uint2 u = x2[q];
            xrh[q*4+0]=bfu(u.x,0); xrh[q*4+1]=bfu(u.x,1);
            xrh[q*4+2]=bfu(u.y,0); xrh[q*4+3]=bfu(u.y,1);
        }
        const float4* a4 = (const float4*)(att_l + hh*HCH);
        #pragma unroll
        for(int q=0;q<3;q++){
            float4 f = a4[q];
            ath[q*4+0]=f.x; ath[q*4+1]=f.y; ath[q*4+2]=f.z; ath[q*4+3]=f.w;
        }
    }
    float m = -3.0e38f, z = 0.f;
    float acc0 = 0.f, acc1 = 0.f;
    const int c0 = lane;
    const int c1 = 64 + (lane & 31);
    const int hd0 = c0 / HCH;
    const int hd1 = c1 / HCH;
    // ---- pipeline prologue: tile0 rows + tile1 metadata ----
    int eA = r0 + e_loc;
    bool vA = eA < r1;
    int4 ecA = vA ? epk[eA] : make_int4(0,0,0,0);
    uint2 xaA[3] = {{0,0},{0,0},{0,0}}, ebA[3] = {{0,0},{0,0},{0,0}};
    if(vA){
        const uint2* xa = (const uint2*)(xl + (size_t)ecA.x*HIDC + hh*HCH);
        const uint2* eb = (const uint2*)(eW + (size_t)ecA.y*HIDC + hh*HCH);
        xaA[0]=xa[0]; xaA[1]=xa[1]; xaA[2]=xa[2];
        ebA[0]=eb[0]; ebA[1]=eb[1]; ebA[2]=eb[2];
    }
    int4 ecB = (eA + 8 < r1) ? epk[eA + 8] : make_int4(0,0,0,0);
    for(int base = r0; base < r1; base += 8){
        // issue next tile's row gathers + next-next metadata (hidden under compute)
        bool vB = (base + 8 + e_loc) < r1;
        uint2 xaB[3] = {{0,0},{0,0},{0,0}}, ebB[3] = {{0,0},{0,0},{0,0}};
        if(vB){
            const uint2* xa = (const uint2*)(xl + (size_t)ecB.x*HIDC + hh*HCH);
            const uint2* eb = (const uint2*)(eW + (size_t)ecB.y*HIDC + hh*HCH);
            xaB[0]=xa[0]; xaB[1]=xa[1]; xaB[2]=xa[2];
            ebB[0]=eb[0]; ebB[1]=eb[1]; ebB[2]=eb[2];
        }
        int eC = base + 16 + e_loc;
        int4 ecC = (eC < r1) ? epk[eC] : make_int4(0,0,0,0);
        // logits from current-tile registers
        float ew = __int_as_float(ecA.z);
        float lg = -3.0e38f;
        if(vA){
            float dot = 0.f;
            #pragma unroll
            for(int q=0;q<3;q++){
                unsigned ux[2] = {xaA[q].x, xaA[q].y};
                unsigned ue[2] = {ebA[q].x, ebA[q].y};
                #pragma unroll
                for(int k2=0;k2<4;k2++){
                    float v = bfu(ux[k2>>1], k2&1) + xrh[q*4+k2] + bfu(ue[k2>>1], k2&1);
                    v = (v > 0.f) ? v : ATT_SLOPE*v;
                    dot += v * ath[q*4+k2];
                }
            }
            lg = dot;
        }
        // stage xl chunk (zeros for invalid)
        uint2* d2 = (uint2*)(&xls[wid][e_loc][hh*HCH]);
        d2[0]=xaA[0]; d2[1]=xaA[1]; d2[2]=xaA[2];
        // online softmax (reduce over e-bits = lane bits 3..5)
        float tm = lg;
        tm = fmaxf(tm, __shfl_xor(tm, 8));
        tm = fmaxf(tm, __shfl_xor(tm, 16));
        tm = fmaxf(tm, __shfl_xor(tm, 32));
        float mn = fmaxf(m, tm);
        float sc = __expf(m - mn);
        float p  = __expf(lg - mn);
        float zt = p;
        zt += __shfl_xor(zt, 8); zt += __shfl_xor(zt, 16); zt += __shfl_xor(zt, 32);
        z = z*sc + zt;
        m = mn;
        pl[wid][e_loc][hh] = p * ew;
        if(lane < NHEAD) sS[wid][lane] = sc;
        __builtin_amdgcn_wave_barrier();
        asm volatile("" ::: "memory");
        float s0 = sS[wid][hd0];
        float a0 = 0.f;
        #pragma unroll
        for(int e=0;e<8;e++)
            a0 += pl[wid][e][hd0] * __bfloat162float(xls[wid][e][c0]);
        acc0 = acc0*s0 + a0;
        if(lane < 32){
            float s1 = sS[wid][hd1];
            float a1 = 0.f;
            #pragma unroll
            for(int e=0;e<8;e++)
                a1 += pl[wid][e][hd1] * __bfloat162float(xls[wid][e][c1]);
            acc1 = acc1*s1 + a1;
        }
        asm volatile("" ::: "memory");
        __builtin_amdgcn_wave_barrier();
        // rotate pipeline registers
        vA = vB; ecA = ecB; ecB = ecC;
        xaA[0]=xaB[0]; xaA[1]=xaB[1]; xaA[2]=xaB[2];
        ebA[0]=ebB[0]; ebA[1]=ebB[1]; ebA[2]=ebB[2];
    }
    if(lane < NHEAD) zS[wid][lane] = z;
    __builtin_amdgcn_wave_barrier();
    asm volatile("" ::: "memory");
    float z0 = zS[wid][hd0];
    h[(size_t)n*HIDC + c0] += acc0/(z0 + 1e-16f) + gbias_l[c0];
    if(lane < 32){
        float z1 = zS[wid][hd1];
        h[(size_t)n*HIDC + c1] += acc1/(z1 + 1e-16f) + gbias_l[c1];
    }
}

// ---------------- launch ----------------
extern "C" void kernel_launch(void* const* d_in, const int* in_sizes, int n_in,
                              void* d_out, int out_size, void* d_ws, size_t ws_size,
                              hipStream_t stream) {
    (void)in_sizes; (void)n_in; (void)out_size; (void)ws_size;
    const float* x          = (const float*)d_in[0];
    const int*   edge_index = (const int*)  d_in[1];
    const float* edge_weight= (const float*)d_in[2];
    const int*   edge_code  = (const int*)  d_in[3];
    const float* edge_emb   = (const float*)d_in[4];
    const float* lin_in_W   = (const float*)d_in[5];
    const float* lin_in_b   = (const float*)d_in[6];
    const float* gn0_w      = (const float*)d_in[7];
    const float* gn0_b      = (const float*)d_in[8];
    const float* gn0_ms     = (const float*)d_in[9];
    const float* Wl         = (const float*)d_in[10];
    const float* bl         = (const float*)d_in[11];
    const float* Wr         = (const float*)d_in[12];
    const float* br         = (const float*)d_in[13];
    const float* We         = (const float*)d_in[14];
    const float* att        = (const float*)d_in[15];
    const float* gbias      = (const float*)d_in[16];
    const float* gn_w       = (const float*)d_in[17];
    const float* gn_b       = (const float*)d_in[18];
    const float* gn_ms      = (const float*)d_in[19];
    const float* lin_out_W  = (const float*)d_in[20];
    const float* lin_out_b  = (const float*)d_in[21];
    float* out = (float*)d_out;

    char* ws = (char*)d_ws;
    size_t off = 0;
    auto alloc = [&](size_t bytes)->void*{ void* p = ws + off; off += (bytes + 255) & ~(size_t)255; return p; };
    float* h     = (float*)alloc((size_t)NN*HIDC*4);
    bf16*  xl    = (bf16*) alloc((size_t)NN*HIDC*2);
    bf16*  xr    = (bf16*) alloc((size_t)NN*HIDC*2);
    bf16*  eWa   = (bf16*) alloc((size_t)NLAY*EVOC*HIDC*2);
    bf16*  wlt   = (bf16*) alloc((size_t)NLAY*HIDC*HIDC*2);
    bf16*  wrt   = (bf16*) alloc((size_t)NLAY*HIDC*HIDC*2);
    bf16*  wint  = (bf16*) alloc((size_t)FIN*HIDC*2);
    float* partial=(float*)alloc((size_t)GN_BLOCKS*2*HIDC*4);
    float* scale = (float*)alloc(HIDC*4);
    float* shift = (float*)alloc(HIDC*4);
    int* rowptr  = (int*)alloc((size_t)(NN+1)*4);
    int* cursor  = (int*)alloc((size_t)NN*4);
    int* pre     = (int*)alloc((size_t)NN*4);
    int* bsum    = (int*)alloc((size_t)NSCB*4);
    int* boffs   = (int*)alloc((size_t)NSCB*4);
    int4* epk    = (int4*)alloc((size_t)NE*16);

    const int* src = edge_index;
    const int* dst = edge_index + NE;

    // CSR build (dst constant across layers -> built once per call)
    hipMemsetAsync(cursor, 0, (size_t)NN*4, stream);
    k_hist<<<(NE+255)/256, 256, 0, stream>>>(dst, cursor);
    k_scan1<<<NSCB, 256, 0, stream>>>(cursor, pre, bsum);
    k_scan2<<<1, 256, 0, stream>>>(bsum, boffs);
    k_scan3<<<NSCB, 256, 0, stream>>>(pre, boffs, rowptr);
    hipMemsetAsync(cursor, 0, (size_t)NN*4, stream);
    k_scatter<<<(NE+255)/256, 256, 0, stream>>>(src, dst, edge_code, edge_weight,
                                                rowptr, cursor, epk);

    // weight transposes (bf16) for MFMA B-fragments
    k_tr<<<dim3((HIDC*HIDC+255)/256, NLAY), 256, 0, stream>>>(Wl, wlt, HIDC, HIDC);
    k_tr<<<dim3((HIDC*HIDC+255)/256, NLAY), 256, 0, stream>>>(Wr, wrt, HIDC, HIDC);
    k_tr<<<dim3((FIN*HIDC+255)/256, 1), 256, 0, stream>>>(lin_in_W, wint, FIN, HIDC);

    // edge-vocab transform, all 6 layers: eWa[l] = edge_emb @ We[l]
    k_gemm<EDIM,HIDC,bf16><<<dim3((EVOC+63)/64, NLAY), 256, 0, stream>>>(
        edge_emb, We, nullptr, eWa, EVOC, EDIM*HIDC, EVOC*HIDC);

    // lin_in -> h (fp32 out, bf16 MFMA inputs)
    k_mfgemm<FIN,false,false,float><<<(NN+63)/64, 256, 0, stream>>>(
        x, wint, lin_in_b, nullptr, nullptr, nullptr, nullptr, 0.f, h, nullptr, NN);

    // gn0 (no activation), in-place on h
    k_gn_reduce<<<GN_BLOCKS, 384, 0, stream>>>(h, partial);
    k_gn_finalize<<<1, 768, 0, stream>>>(partial, gn0_w, gn0_b, gn0_ms, scale, shift);
    k_gn_apply<<<768, 384, 0, stream>>>(h, scale, shift, h, 1.0f);

    for(int l=0;l<NLAY;l++){
        k_gn_reduce<<<GN_BLOCKS, 384, 0, stream>>>(h, partial);
        k_gn_finalize<<<1, 768, 0, stream>>>(partial, gn_w + l*HIDC, gn_b + l*HIDC, gn_ms + l*HIDC, scale, shift);
        // fused dual MFMA GEMM: GN+LeakyReLU in A-stage, xl & xr in one pass
        k_mfgemm<HIDC,true,true,bf16><<<(NN+63)/64, 256, 0, stream>>>(
            h, wlt + (size_t)l*HIDC*HIDC, bl + l*HIDC,
               wrt + (size_t)l*HIDC*HIDC, br + l*HIDC,
            scale, shift, ACT_SLOPE, xl, xr, NN);
        // fused logits + online softmax + aggregate + residual (wave per node)
        k_gat<<<(NN+3)/4, 256, 0, stream>>>(rowptr, epk, xl, xr,
                                            eWa + (size_t)l*EVOC*HIDC, att + l*NHEAD*HCH,
                                            gbias + l*HIDC, h);
    }

    // lin_out -> d_out (fp32)
    k_gemm<HIDC,FOUT,float><<<(NN+63)/64, 256, 0, stream>>>(
        h, lin_out_W, lin_out_b, out, NN, 0, 0);
}

// Round 7
// 660.626 us; speedup vs baseline: 3.7336x; 1.1722x over previous
//
#include <hip/hip_runtime.h>
#include <hip/hip_bf16.h>

// Problem constants
constexpr int NN   = 50000;   // nodes
constexpr int NE   = 800000;  // edges
constexpr int FIN  = 128;
constexpr int HIDC = 96;
constexpr int FOUT = 64;
constexpr int NHEAD= 8;
constexpr int HCH  = 12;
constexpr int NLAY = 6;
constexpr int EVOC = 1000;
constexpr int EDIM = 32;
constexpr float ACT_SLOPE = 0.01f;
constexpr float ATT_SLOPE = 0.2f;
constexpr float GN_EPS = 1e-5f;
constexpr int GN_BLOCKS = 256;
constexpr int NSCB = (NN + 255)/256;   // scan blocks (196)

typedef __hip_bfloat16 bf16;
typedef __attribute__((ext_vector_type(8))) short bf16x8;
typedef __attribute__((ext_vector_type(4))) float f32x4;

__device__ __forceinline__ float bfu(unsigned u, int hi){
    return __uint_as_float(hi ? (u & 0xffff0000u) : (u << 16));
}

// ---------------- CSR build ----------------
__global__ void k_hist(const int* __restrict__ dst, int* __restrict__ deg){
    int e = blockIdx.x*blockDim.x + threadIdx.x;
    if(e < NE) atomicAdd(&deg[dst[e]], 1);
}

__global__ __launch_bounds__(256) void k_scan1(const int* __restrict__ deg,
        int* __restrict__ pre, int* __restrict__ bsum){
    __shared__ int s[256];
    int tid = threadIdx.x;
    int idx = blockIdx.x*256 + tid;
    int v = (idx < NN) ? deg[idx] : 0;
    s[tid] = v; __syncthreads();
    #pragma unroll
    for(int off=1; off<256; off<<=1){
        int t = (tid>=off) ? s[tid-off] : 0;
        __syncthreads();
        s[tid] += t;
        __syncthreads();
    }
    if(idx < NN) pre[idx] = s[tid] - v;          // exclusive
    if(tid == 255) bsum[blockIdx.x] = s[255];    // block total
}

__global__ __launch_bounds__(256) void k_scan2(const int* __restrict__ bsum,
        int* __restrict__ boffs){
    __shared__ int s[256];
    int tid = threadIdx.x;
    int v = (tid < NSCB) ? bsum[tid] : 0;
    s[tid] = v; __syncthreads();
    #pragma unroll
    for(int off=1; off<256; off<<=1){
        int t = (tid>=off) ? s[tid-off] : 0;
        __syncthreads();
        s[tid] += t;
        __syncthreads();
    }
    if(tid < NSCB) boffs[tid] = s[tid] - v;      // exclusive
}

__global__ __launch_bounds__(256) void k_scan3(const int* __restrict__ pre,
        const int* __restrict__ boffs, int* __restrict__ rowptr, int* __restrict__ cursor){
    int tid = threadIdx.x;
    int idx = blockIdx.x*256 + tid;
    if(idx < NN){
        rowptr[idx] = pre[idx] + boffs[blockIdx.x];
        cursor[idx] = 0;                         // re-zero for scatter
    }
    if(blockIdx.x == 0 && tid == 0) rowptr[NN] = NE;
}

__global__ void k_scatter(const int* __restrict__ src, const int* __restrict__ dst,
                          const int* __restrict__ code, const float* __restrict__ ew,
                          const int* __restrict__ rowptr, int* __restrict__ cursor,
                          int4* __restrict__ epk){
    int e = blockIdx.x*blockDim.x + threadIdx.x;
    if(e >= NE) return;
    int d = dst[e];
    int pos = rowptr[d] + atomicAdd(&cursor[d], 1);
    epk[pos] = make_int4(src[e], code[e], __float_as_int(ew[e]), 0);
}

// ------- transpose + bf16-pack ALL weights in one launch -------
// segs: 0..5 Wl[96x96], 6..11 Wr[96x96], 12 lin_in_W[128x96], 13 lin_out_W[96x64]
__global__ __launch_bounds__(256) void k_trall(const float* __restrict__ Wl,
        const float* __restrict__ Wr, const float* __restrict__ Win, const float* __restrict__ Wout,
        bf16* __restrict__ wlt, bf16* __restrict__ wrt, bf16* __restrict__ wint, bf16* __restrict__ wot){
    int seg = blockIdx.y;
    const float* W; bf16* Wt; int K, N;
    if(seg < 6)      { W = Wl  + seg*9216;     Wt = wlt + seg*9216;     K = 96;  N = 96; }
    else if(seg < 12){ W = Wr  + (seg-6)*9216; Wt = wrt + (seg-6)*9216; K = 96;  N = 96; }
    else if(seg==12) { W = Win;                Wt = wint;               K = 128; N = 96; }
    else             { W = Wout;               Wt = wot;                K = 96;  N = 64; }
    int i = blockIdx.x*256 + threadIdx.x;
    if(i >= K*N) return;
    int k = i / N, nn = i - k*N;
    Wt[(size_t)nn*K + k] = __float2bfloat16(W[i]);
}

// -------- small GEMM (fp32 VALU; used for eWa only) --------
template<int K, int NC, typename OT>
__global__ __launch_bounds__(256) void k_gemm(const float* __restrict__ A,
        const float* __restrict__ W, const float* __restrict__ bias,
        OT* __restrict__ C, int M, int wstride, int cstride){
    constexpr int CPT = NC/16;
    W += (size_t)blockIdx.y * wstride;
    C += (size_t)blockIdx.y * cstride;
    __shared__ float At[K][68];
    int tid = threadIdx.x;
    int m0 = blockIdx.x*64;
    for(int i=tid; i<64*K; i+=256){
        int r = i / K, k = i - r*K;
        int row = m0 + r;
        At[k][r] = (row < M) ? A[(size_t)row*K + k] : 0.f;
    }
    __syncthreads();
    int tr = tid>>4, tc = tid&15;
    const float* wr = W + tc*CPT;
    float acc[4][CPT];
    #pragma unroll
    for(int i=0;i<4;i++)
        #pragma unroll
        for(int j=0;j<CPT;j++) acc[i][j]=0.f;
    #pragma unroll 4
    for(int k=0;k<K;k++){
        float a[4], w[CPT];
        #pragma unroll
        for(int i=0;i<4;i++) a[i] = At[k][tr*4+i];
        #pragma unroll
        for(int j=0;j<CPT;j++) w[j] = wr[k*NC + j];
        #pragma unroll
        for(int i=0;i<4;i++)
            #pragma unroll
            for(int j=0;j<CPT;j++) acc[i][j] += a[i]*w[j];
    }
    #pragma unroll
    for(int i=0;i<4;i++){
        int row = m0 + tr*4 + i;
        if(row < M){
            OT* cp = C + (size_t)row*NC + tc*CPT;
            #pragma unroll
            for(int j=0;j<CPT;j++){
                float v = acc[i][j] + (bias ? bias[tc*CPT+j] : 0.f);
                if constexpr (sizeof(OT)==2) cp[j] = __float2bfloat16(v);
                else cp[j] = v;
            }
        }
    }
}

// -------- MFMA GEMM: C[M,NC] = f(A[M,K]) @ W (optionally dual), f = GN+LeakyReLU --------
// Wt pre-transposed bf16 [n][k]. A staged to LDS as bf16 (GN applied in stage).
template<int K, int NC, bool GN, bool DUAL, typename OT>
__global__ __launch_bounds__(256) void k_mfgemm(const float* __restrict__ A,
        const bf16* __restrict__ W1t, const float* __restrict__ b1,
        const bf16* __restrict__ W2t, const float* __restrict__ b2,
        const float* __restrict__ gscale, const float* __restrict__ gshift, float slope,
        OT* __restrict__ C1, OT* __restrict__ C2, int M){
    constexpr int KP = K + 8;
    constexpr int F4R = K/4;
    constexpr int NF4 = 64*F4R;
    constexpr int KS = K/32;
    constexpr int NT = NC/16;
    __shared__ bf16 At[64][KP];
    int tid = threadIdx.x;
    int m0 = blockIdx.x*64;
    for(int idx = tid; idx < NF4; idx += 256){
        int r = idx / F4R, c4 = idx - r*F4R;
        int row = m0 + r;
        float4 v = (row < M) ? ((const float4*)A)[(size_t)row*F4R + c4]
                             : make_float4(0.f,0.f,0.f,0.f);
        float vv[4] = {v.x, v.y, v.z, v.w};
        bf16* dp = &At[r][c4*4];
        #pragma unroll
        for(int c=0;c<4;c++){
            float u = vv[c];
            if constexpr (GN){
                int k = c4*4 + c;
                u = gscale[k]*u + gshift[k];
                u = (u > 0.f) ? u : slope*u;
            }
            dp[c] = __float2bfloat16(u);
        }
    }
    __syncthreads();
    int w = tid >> 6, l = tid & 63;
    int mrow = l & 15;
    int kg = (l >> 4) * 8;
    f32x4 acc1[NT], acc2[NT];
    #pragma unroll
    for(int nt=0; nt<NT; nt++){
        acc1[nt] = (f32x4){0.f,0.f,0.f,0.f};
        if constexpr (DUAL) acc2[nt] = (f32x4){0.f,0.f,0.f,0.f};
    }
    const bf16* a_base = &At[w*16 + mrow][0];
    #pragma unroll
    for(int ks=0; ks<KS; ks++){
        bf16x8 a = *(const bf16x8*)(a_base + ks*32 + kg);
        #pragma unroll
        for(int nt=0; nt<NT; nt++){
            int n = nt*16 + mrow;
            bf16x8 bfr = *(const bf16x8*)(W1t + (size_t)n*K + ks*32 + kg);
            acc1[nt] = __builtin_amdgcn_mfma_f32_16x16x32_bf16(a, bfr, acc1[nt], 0,0,0);
            if constexpr (DUAL){
                bf16x8 bfr2 = *(const bf16x8*)(W2t + (size_t)n*K + ks*32 + kg);
                acc2[nt] = __builtin_amdgcn_mfma_f32_16x16x32_bf16(a, bfr2, acc2[nt], 0,0,0);
            }
        }
    }
    int rbase = m0 + w*16 + (l>>4)*4;
    #pragma unroll
    for(int nt=0; nt<NT; nt++){
        int n = nt*16 + mrow;
        float bb1 = b1[n];
        float bb2 = 0.f;
        if constexpr (DUAL) bb2 = b2[n];
        #pragma unroll
        for(int r=0;r<4;r++){
            int row = rbase + r;
            if(row < M){
                float v1 = acc1[nt][r] + bb1;
                if constexpr (sizeof(OT)==2) C1[(size_t)row*NC + n] = __float2bfloat16(v1);
                else                         C1[(size_t)row*NC + n] = v1;
                if constexpr (DUAL){
                    float v2 = acc2[nt][r] + bb2;
                    C2[(size_t)row*NC + n] = __float2bfloat16(v2);
                }
            }
        }
    }
}

// ---------------- GraphNorm stats (float4 loads) ----------------
__global__ __launch_bounds__(384) void k_gn_reduce(const float* __restrict__ x, float* __restrict__ partial){
    int tid = threadIdx.x;
    const float4* x4 = (const float4*)x;
    constexpr int TOT4 = NN*HIDC/4;
    const int stride = GN_BLOCKS*384;
    float s0=0,s1=0,s2=0,s3=0, q0=0,q1=0,q2=0,q3=0;
    for(int i = blockIdx.x*384 + tid; i < TOT4; i += stride){
        float4 v = x4[i];
        s0+=v.x; q0+=v.x*v.x;
        s1+=v.y; q1+=v.y*v.y;
        s2+=v.z; q2+=v.z*v.z;
        s3+=v.w; q3+=v.w*v.w;
    }
    __shared__ float ls[384][4], lq[384][4];
    ls[tid][0]=s0; ls[tid][1]=s1; ls[tid][2]=s2; ls[tid][3]=s3;
    lq[tid][0]=q0; lq[tid][1]=q1; lq[tid][2]=q2; lq[tid][3]=q3;
    __syncthreads();
    if(tid < 96){
        int g = tid >> 2, c = tid & 3;   // g < 24
        float a=0.f, b=0.f;
        #pragma unroll
        for(int j=0;j<16;j++){
            a += ls[g + 24*j][c];
            b += lq[g + 24*j][c];
        }
        partial[blockIdx.x*192 + g*4 + c]      = a;
        partial[blockIdx.x*192 + 96 + g*4 + c] = b;
    }
}

__global__ __launch_bounds__(768) void k_gn_finalize(const float* __restrict__ partial,
        const float* __restrict__ w, const float* __restrict__ b, const float* __restrict__ ms,
        float* __restrict__ scale, float* __restrict__ shift){
    __shared__ float red[4][192];
    int tid = threadIdx.x;
    int v = tid % 192, seg = tid / 192;
    float s = 0.f;
    #pragma unroll 8
    for(int bk=seg; bk<GN_BLOCKS; bk+=4) s += partial[bk*192 + v];
    red[seg][v] = s;
    __syncthreads();
    if(tid < 192) red[0][tid] = red[0][tid]+red[1][tid]+red[2][tid]+red[3][tid];
    __syncthreads();
    if(tid < HIDC){
        float mean = red[0][tid] / (float)NN;
        float m2   = red[0][tid+96] / (float)NN;
        float mm   = ms[tid]*mean;
        float var  = m2 - 2.f*mm*mean + mm*mm;
        float sc   = w[tid] * rsqrtf(var + GN_EPS);
        scale[tid] = sc;
        shift[tid] = b[tid] - sc*mm;
    }
}

__global__ __launch_bounds__(384) void k_gn_apply(const float* __restrict__ x,
        const float* __restrict__ scale, const float* __restrict__ shift,
        float* __restrict__ out, float slope){
    int tid = threadIdx.x;
    int c = tid % HIDC;
    float sc = scale[c], sh = shift[c];
    const int total = NN*HIDC;
    const int stride = gridDim.x*384;
    for(int i=blockIdx.x*384+tid; i<total; i+=stride){
        float v = sc*x[i] + sh;
        out[i] = (v > 0.f) ? v : slope*v;
    }
}

// ---- fused GATv2 edge path: wave-per-node, ZERO LDS, register-only aggregation ----
// lane = (e_loc<<3)|hh. Lane (e,hh) computes edge e's head-hh logit from its 12
// channels, keeps p in-register, and accumulates p*ew*xl into acc[12] (same 12
// channels = head hh's output channels). Softmax stats via shfl over e-bits
// (8/16/32); final cross-e reduction of acc via 36 shfls; 8 lanes write h.
__global__ __launch_bounds__(256, 6) void k_gat(const int* __restrict__ rowptr,
        const int4* __restrict__ epk,
        const bf16* __restrict__ xl, const bf16* __restrict__ xr,
        const bf16* __restrict__ eW, const float* __restrict__ att_l,
        const float* __restrict__ gbias_l, float* __restrict__ h){
    int wid  = threadIdx.x >> 6;
    int lane = threadIdx.x & 63;
    int n = blockIdx.x*4 + wid;
    if(n >= NN) return;
    int r0 = rowptr[n], r1 = rowptr[n+1];
    int e_loc = lane >> 3, hh = lane & 7;
    // hoisted invariants for head hh: xr chunk + att chunk (12 ch each)
    float xrv[HCH], atv[HCH];
    {
        const uint2* x2 = (const uint2*)(xr + (size_t)n*HIDC + hh*HCH);
        #pragma unroll
        for(int q=0;q<3;q++){
            uint2 u = x2[q];
            xrv[q*4+0]=bfu(u.x,0); xrv[q*4+1]=bfu(u.x,1);
            xrv[q*4+2]=bfu(u.y,0); xrv[q*4+3]=bfu(u.y,1);
        }
        const float4* a4 = (const float4*)(att_l + hh*HCH);
        #pragma unroll
        for(int q=0;q<3;q++){
            float4 f = a4[q];
            atv[q*4+0]=f.x; atv[q*4+1]=f.y; atv[q*4+2]=f.z; atv[q*4+3]=f.w;
        }
    }
    float m = -3.0e38f, z = 0.f;
    float acc[HCH];
    #pragma unroll
    for(int q=0;q<HCH;q++) acc[q]=0.f;
    for(int base = r0; base < r1; base += 8){
        int eidx = base + e_loc;
        bool val = eidx < r1;
        float xv[HCH];
        float lg = -3.0e38f, ew = 0.f;
        if(val){
            int4 ec = epk[eidx];
            ew = __int_as_float(ec.z);
            const uint2* xa2 = (const uint2*)(xl + (size_t)ec.x*HIDC + hh*HCH);
            const uint2* eb2 = (const uint2*)(eW + (size_t)ec.y*HIDC + hh*HCH);
            uint2 xa[3] = {xa2[0], xa2[1], xa2[2]};
            uint2 eb[3] = {eb2[0], eb2[1], eb2[2]};
            float dot = 0.f;
            #pragma unroll
            for(int q=0;q<3;q++){
                unsigned ux[2] = {xa[q].x, xa[q].y};
                unsigned ue[2] = {eb[q].x, eb[q].y};
                #pragma unroll
                for(int k2=0;k2<4;k2++){
                    int c = q*4 + k2;
                    float xf = bfu(ux[k2>>1], k2&1);
                    xv[c] = xf;
                    float v = xf + xrv[c] + bfu(ue[k2>>1], k2&1);
                    v = fmaxf(v, ATT_SLOPE*v);   // leaky relu (slope<1)
                    dot += v * atv[c];
                }
            }
            lg = dot;
        } else {
            #pragma unroll
            for(int q=0;q<HCH;q++) xv[q]=0.f;
        }
        // online softmax, per head (reduce over e-bits = lane bits 3..5)
        float tm = lg;
        tm = fmaxf(tm, __shfl_xor(tm, 8));
        tm = fmaxf(tm, __shfl_xor(tm, 16));
        tm = fmaxf(tm, __shfl_xor(tm, 32));
        float mn = fmaxf(m, tm);
        float sc = __expf(m - mn);    // first tile: 0
        float p  = __expf(lg - mn);   // invalid lanes: 0
        float zt = p;
        zt += __shfl_xor(zt, 8); zt += __shfl_xor(zt, 16); zt += __shfl_xor(zt, 32);
        z = z*sc + zt;
        m = mn;
        float pw = p * ew;
        #pragma unroll
        for(int q=0;q<HCH;q++) acc[q] = acc[q]*sc + pw*xv[q];
    }
    // cross-e reduction of acc (all e-lanes end with head-hh channel sums)
    #pragma unroll
    for(int q=0;q<HCH;q++){
        float a = acc[q];
        a += __shfl_xor(a, 8);
        a += __shfl_xor(a, 16);
        a += __shfl_xor(a, 32);
        acc[q] = a;
    }
    if(e_loc == 0){
        float inv = 1.f/(z + 1e-16f);
        float4* hp4 = (float4*)(h + (size_t)n*HIDC + hh*HCH);
        const float4* gb4 = (const float4*)(gbias_l + hh*HCH);
        #pragma unroll
        for(int q3=0;q3<3;q3++){
            float4 hv = hp4[q3], gv = gb4[q3];
            hv.x += acc[q3*4+0]*inv + gv.x;
            hv.y += acc[q3*4+1]*inv + gv.y;
            hv.z += acc[q3*4+2]*inv + gv.z;
            hv.w += acc[q3*4+3]*inv + gv.w;
            hp4[q3] = hv;
        }
    }
}

// ---------------- launch ----------------
extern "C" void kernel_launch(void* const* d_in, const int* in_sizes, int n_in,
                              void* d_out, int out_size, void* d_ws, size_t ws_size,
                              hipStream_t stream) {
    (void)in_sizes; (void)n_in; (void)out_size; (void)ws_size;
    const float* x          = (const float*)d_in[0];
    const int*   edge_index = (const int*)  d_in[1];
    const float* edge_weight= (const float*)d_in[2];
    const int*   edge_code  = (const int*)  d_in[3];
    const float* edge_emb   = (const float*)d_in[4];
    const float* lin_in_W   = (const float*)d_in[5];
    const float* lin_in_b   = (const float*)d_in[6];
    const float* gn0_w      = (const float*)d_in[7];
    const float* gn0_b      = (const float*)d_in[8];
    const float* gn0_ms     = (const float*)d_in[9];
    const float* Wl         = (const float*)d_in[10];
    const float* bl         = (const float*)d_in[11];
    const float* Wr         = (const float*)d_in[12];
    const float* br         = (const float*)d_in[13];
    const float* We         = (const float*)d_in[14];
    const float* att        = (const float*)d_in[15];
    const float* gbias      = (const float*)d_in[16];
    const float* gn_w       = (const float*)d_in[17];
    const float* gn_b       = (const float*)d_in[18];
    const float* gn_ms      = (const float*)d_in[19];
    const float* lin_out_W  = (const float*)d_in[20];
    const float* lin_out_b  = (const float*)d_in[21];
    float* out = (float*)d_out;

    char* ws = (char*)d_ws;
    size_t off = 0;
    auto alloc = [&](size_t bytes)->void*{ void* p = ws + off; off += (bytes + 255) & ~(size_t)255; return p; };
    float* h     = (float*)alloc((size_t)NN*HIDC*4);
    bf16*  xl    = (bf16*) alloc((size_t)NN*HIDC*2);
    bf16*  xr    = (bf16*) alloc((size_t)NN*HIDC*2);
    bf16*  eWa   = (bf16*) alloc((size_t)NLAY*EVOC*HIDC*2);
    bf16*  wlt   = (bf16*) alloc((size_t)NLAY*HIDC*HIDC*2);
    bf16*  wrt   = (bf16*) alloc((size_t)NLAY*HIDC*HIDC*2);
    bf16*  wint  = (bf16*) alloc((size_t)FIN*HIDC*2);
    bf16*  wot   = (bf16*) alloc((size_t)HIDC*FOUT*2);
    float* partial=(float*)alloc((size_t)GN_BLOCKS*2*HIDC*4);
    float* scale = (float*)alloc(HIDC*4);
    float* shift = (float*)alloc(HIDC*4);
    int* rowptr  = (int*)alloc((size_t)(NN+1)*4);
    int* cursor  = (int*)alloc((size_t)NN*4);
    int* pre     = (int*)alloc((size_t)NN*4);
    int* bsum    = (int*)alloc((size_t)NSCB*4);
    int* boffs   = (int*)alloc((size_t)NSCB*4);
    int4* epk    = (int4*)alloc((size_t)NE*16);

    const int* src = edge_index;
    const int* dst = edge_index + NE;

    // CSR build (dst constant across layers -> built once per call)
    hipMemsetAsync(cursor, 0, (size_t)NN*4, stream);
    k_hist<<<(NE+255)/256, 256, 0, stream>>>(dst, cursor);
    k_scan1<<<NSCB, 256, 0, stream>>>(cursor, pre, bsum);
    k_scan2<<<1, 256, 0, stream>>>(bsum, boffs);
    k_scan3<<<NSCB, 256, 0, stream>>>(pre, boffs, rowptr, cursor);
    k_scatter<<<(NE+255)/256, 256, 0, stream>>>(src, dst, edge_code, edge_weight,
                                                rowptr, cursor, epk);

    // all weight transposes (bf16) in one launch
    k_trall<<<dim3(48, 14), 256, 0, stream>>>(Wl, Wr, lin_in_W, lin_out_W,
                                              wlt, wrt, wint, wot);

    // edge-vocab transform, all 6 layers: eWa[l] = edge_emb @ We[l]
    k_gemm<EDIM,HIDC,bf16><<<dim3((EVOC+63)/64, NLAY), 256, 0, stream>>>(
        edge_emb, We, nullptr, eWa, EVOC, EDIM*HIDC, EVOC*HIDC);

    // lin_in -> h (fp32 out, bf16 MFMA inputs)
    k_mfgemm<FIN,HIDC,false,false,float><<<(NN+63)/64, 256, 0, stream>>>(
        x, wint, lin_in_b, nullptr, nullptr, nullptr, nullptr, 0.f, h, nullptr, NN);

    // gn0 (no activation), in-place on h
    k_gn_reduce<<<GN_BLOCKS, 384, 0, stream>>>(h, partial);
    k_gn_finalize<<<1, 768, 0, stream>>>(partial, gn0_w, gn0_b, gn0_ms, scale, shift);
    k_gn_apply<<<768, 384, 0, stream>>>(h, scale, shift, h, 1.0f);

    for(int l=0;l<NLAY;l++){
        k_gn_reduce<<<GN_BLOCKS, 384, 0, stream>>>(h, partial);
        k_gn_finalize<<<1, 768, 0, stream>>>(partial, gn_w + l*HIDC, gn_b + l*HIDC, gn_ms + l*HIDC, scale, shift);
        // fused dual MFMA GEMM: GN+LeakyReLU in A-stage, xl & xr in one pass
        k_mfgemm<HIDC,HIDC,true,true,bf16><<<(NN+63)/64, 256, 0, stream>>>(
            h, wlt + (size_t)l*HIDC*HIDC, bl + l*HIDC,
               wrt + (size_t)l*HIDC*HIDC, br + l*HIDC,
            scale, shift, ACT_SLOPE, xl, xr, NN);
        // fused logits + online softmax + aggregate + residual (wave per node, no LDS)
        k_gat<<<(NN+3)/4, 256, 0, stream>>>(rowptr, epk, xl, xr,
                                            eWa + (size_t)l*EVOC*HIDC, att + l*NHEAD*HCH,
                                            gbias + l*HIDC, h);
    }

    // lin_out -> d_out (fp32 out, bf16 MFMA inputs)
    k_mfgemm<HIDC,FOUT,false,false,float><<<(NN+63)/64, 256, 0, stream>>>(
        h, wot, lin_out_b, nullptr, nullptr, nullptr, nullptr, 0.f, out, nullptr, NN);
}